// Round 14
// baseline (362.098 us; speedup 1.0000x reference)
//
#include <hip/hip_runtime.h>
#include <stdint.h>

typedef __attribute__((ext_vector_type(4))) float f32x4;
typedef __attribute__((ext_vector_type(16))) float f32x16;
typedef __attribute__((ext_vector_type(8))) short bf16x8;
typedef unsigned short u16;

#define MFMA(a, b, c) __builtin_amdgcn_mfma_f32_16x16x32_bf16(a, b, c, 0, 0, 0)
#define MFMA32(a, b, c) __builtin_amdgcn_mfma_f32_32x32x16_bf16(a, b, c, 0, 0, 0)
#define EXP2(x) __builtin_amdgcn_exp2f(x)
#define FENCE asm volatile("" ::: "memory")
#define BARRIER do { FENCE; __builtin_amdgcn_s_barrier(); FENCE; } while (0)

__device__ __forceinline__ u16 f2bf(float f) {
  union { float f; unsigned u; } x; x.f = f;
  unsigned r = x.u + 0x7fffu + ((x.u >> 16) & 1u);
  return (u16)(r >> 16);
}

__device__ __forceinline__ unsigned cvtpk(float lo, float hi) {
  unsigned r;
  asm("v_cvt_pk_bf16_f32 %0, %1, %2" : "=v"(r) : "v"(lo), "v"(hi));
  return r;
}

__device__ __forceinline__ void pl32swap(unsigned& a, unsigned& b) {
  asm volatile("v_permlane32_swap_b32 %0, %1" : "+v"(a), "+v"(b));
}

__device__ __forceinline__ void gload16(const void* g, void* l) {
  __builtin_amdgcn_global_load_lds(
      (const __attribute__((address_space(1))) unsigned int*)g,
      (__attribute__((address_space(3))) unsigned int*)l, 16, 0, 0);
}

// ---------------------------------------------------------------- cast f32->bf16
__global__ void __launch_bounds__(256) cast_bf16(const float* __restrict__ in,
                                                 u16* __restrict__ out, int n4) {
  int i = blockIdx.x * 256 + threadIdx.x;
  if (i >= n4) return;
  float4 v = reinterpret_cast<const float4*>(in)[i];
  ushort4 o;
  o.x = f2bf(v.x); o.y = f2bf(v.y); o.z = f2bf(v.z); o.w = f2bf(v.w);
  reinterpret_cast<ushort4*>(out)[i] = o;
}

// ---------------------------------------------------------------- 8-phase 256^2 GEMM (R11, kept)
template <int EPI>
__global__ void __launch_bounds__(512)
gemm8(const u16* __restrict__ A, const u16* __restrict__ B,
      void* __restrict__ C0, void* __restrict__ C1, void* __restrict__ C2,
      int M, int N, int K, int MBt) {
  __shared__ alignas(16) char smb[131072];
  const int tid = threadIdx.x;
  const int w = tid >> 6, lane = tid & 63;
  const int lr = lane & 15, g = lane >> 4;
  const int wm = w >> 2, wn = w & 3;
  const int gb = (blockIdx.x & 7) * ((int)gridDim.x >> 3) + (blockIdx.x >> 3);
  const int mb = gb % MBt, nb = gb / MBt;
  const int m0 = mb * 256, n0 = nb * 256;
  const int NT = K >> 6, NIT = NT >> 1;

  const int l8 = lane >> 3, l7 = lane & 7;
  const int csb = (l7 ^ l8) * 16;
  const char* asrcb[2];
  const char* bsrcb[2];
  unsigned adst[2], bdst[2];
#pragma unroll
  for (int j = 0; j < 2; ++j) {
    int c = 2 * w + j;
    int ra = (c & 7) * 8 + ((c >> 3) << 7) + l8;
    asrcb[j] = (const char*)(A + (size_t)(m0 + ra) * K) + csb;
    adst[j] = (unsigned)(ra * 128 + l7 * 16);
    int rb = (c & 3) * 8 + ((c >> 2) << 6) + l8;
    bsrcb[j] = (const char*)(B + (size_t)(n0 + rb) * K) + csb;
    bdst[j] = (unsigned)(rb * 128 + l7 * 16);
  }
  const size_t arow64 = (size_t)64 * K * 2;
  const size_t brow32 = (size_t)32 * K * 2;

#define STG(kt, u)                                                            \
  do {                                                                        \
    if ((kt) < NT) {                                                          \
      int _d = ((kt) & 1) ? 32768 : 0;                                        \
      size_t _ko = (size_t)(kt) * 128;                                        \
      if ((u) == 0) {                                                         \
        gload16(asrcb[0] + _ko, smb + _d + adst[0]);                          \
        gload16(asrcb[1] + _ko, smb + _d + adst[1]);                          \
      } else if ((u) == 1) {                                                  \
        gload16(bsrcb[0] + _ko, smb + 65536 + _d + bdst[0]);                  \
        gload16(bsrcb[1] + _ko, smb + 65536 + _d + bdst[1]);                  \
      } else if ((u) == 2) {                                                  \
        gload16(asrcb[0] + arow64 + _ko, smb + _d + 8192 + adst[0]);          \
        gload16(asrcb[1] + arow64 + _ko, smb + _d + 8192 + adst[1]);          \
      } else {                                                                \
        gload16(bsrcb[0] + brow32 + _ko, smb + 65536 + _d + 4096 + bdst[0]);  \
        gload16(bsrcb[1] + brow32 + _ko, smb + 65536 + _d + 4096 + bdst[1]);  \
      }                                                                       \
    }                                                                         \
  } while (0)

  f32x4 acc[8][4];
#pragma unroll
  for (int x = 0; x < 8; ++x)
#pragma unroll
    for (int y = 0; y < 4; ++y) acc[x][y] = f32x4{0.f, 0.f, 0.f, 0.f};
  bf16x8 af[4][2], bf01[2][2], bf23[2][2];
  const int aoff0 = ((g) ^ (lr & 7)) << 4;
  const int aoff1 = ((4 + g) ^ (lr & 7)) << 4;
  const int arow = (wm * 128 + lr) * 128;
  const int brow = (wn * 64 + lr) * 128;

  auto LDA = [&](const char* base, int mih) {
#pragma unroll
    for (int mi = 0; mi < 4; ++mi) {
      const char* p = base + arow + (mih * 64 + mi * 16) * 128;
      af[mi][0] = *(const bf16x8*)(p + aoff0);
      af[mi][1] = *(const bf16x8*)(p + aoff1);
    }
  };
  auto LDB = [&](const char* base, bf16x8 (*bfr)[2], int nih) {
#pragma unroll
    for (int ni = 0; ni < 2; ++ni) {
      const char* p = base + brow + (nih * 32 + ni * 16) * 128;
      bfr[ni][0] = *(const bf16x8*)(p + aoff0);
      bfr[ni][1] = *(const bf16x8*)(p + aoff1);
    }
  };
  auto MM = [&](int mih, int nih, bf16x8 (*bfr)[2]) {
    __builtin_amdgcn_s_setprio(1);
#pragma unroll
    for (int mi = 0; mi < 4; ++mi)
#pragma unroll
      for (int ni = 0; ni < 2; ++ni) {
        acc[mih * 4 + mi][nih * 2 + ni] =
            MFMA(af[mi][0], bfr[ni][0], acc[mih * 4 + mi][nih * 2 + ni]);
        acc[mih * 4 + mi][nih * 2 + ni] =
            MFMA(af[mi][1], bfr[ni][1], acc[mih * 4 + mi][nih * 2 + ni]);
      }
    __builtin_amdgcn_s_setprio(0);
  };

  STG(0, 0); STG(0, 1); STG(0, 2); STG(0, 3);
  STG(1, 0); STG(1, 1); STG(1, 2);
  asm volatile("s_waitcnt vmcnt(6)" ::: "memory");
  BARRIER;

  const char* A0 = smb;
  const char* B0 = smb + 65536;
  const char* A1 = smb + 32768;
  const char* B1 = smb + 65536 + 32768;

  for (int it = 0; it < NIT; ++it) {
    const int t0 = 2 * it;
    const bool lastit = (it == NIT - 1);
    LDA(A0, 0); LDB(B0, bf01, 0); STG(t0 + 1, 3);
    BARRIER; MM(0, 0, bf01); BARRIER;
    LDB(B0, bf23, 1); STG(t0 + 2, 0);
    BARRIER; MM(0, 1, bf23); BARRIER;
    LDA(A0, 1); STG(t0 + 2, 1);
    BARRIER; MM(1, 1, bf23); BARRIER;
    STG(t0 + 2, 2);
    if (lastit) asm volatile("s_waitcnt vmcnt(0)" ::: "memory");
    else        asm volatile("s_waitcnt vmcnt(6)" ::: "memory");
    BARRIER; MM(1, 0, bf01); BARRIER;
    LDA(A1, 0); LDB(B1, bf01, 0); STG(t0 + 2, 3);
    BARRIER; MM(0, 0, bf01); BARRIER;
    LDB(B1, bf23, 1); STG(t0 + 3, 0);
    BARRIER; MM(0, 1, bf23); BARRIER;
    LDA(A1, 1); STG(t0 + 3, 1);
    BARRIER; MM(1, 1, bf23); BARRIER;
    STG(t0 + 3, 2);
    asm volatile("s_waitcnt vmcnt(6)" ::: "memory");
    BARRIER; MM(1, 0, bf01); BARRIER;
  }
#undef STG

  if (EPI == 0) {
    const float qs = 0.08838834764831845f * 1.4426950408889634f;
    u16* qo = (u16*)C0;
    u16* ko = (u16*)C1;
    u16* vo = (u16*)C2;
#pragma unroll
    for (int mi = 0; mi < 8; ++mi) {
      int s0 = m0 + wm * 128 + mi * 16 + g * 4;
#pragma unroll
      for (int ni = 0; ni < 4; ++ni) {
        int n = n0 + wn * 64 + ni * 16 + lr;
        int t = n >> 11, hh = (n >> 7) & 15, d = n & 127;
        if (t == 2) {
          ushort4 pk;
          pk.x = f2bf(acc[mi][ni][0]);
          pk.y = f2bf(acc[mi][ni][1]);
          pk.z = f2bf(acc[mi][ni][2]);
          pk.w = f2bf(acc[mi][ni][3]);
          *(ushort4*)(vo + (size_t)(hh * 128 + d) * 4096 + s0) = pk;
        } else {
          float sc = (t == 0) ? qs : 1.f;
          u16* dq = (t == 0 ? qo : ko) + (size_t)(hh * 4096 + s0) * 128 + d;
#pragma unroll
          for (int j = 0; j < 4; ++j) dq[(size_t)j * 128] = f2bf(acc[mi][ni][j] * sc);
        }
      }
    }
  } else {
    float* C = (float*)C0;
#pragma unroll
    for (int mi = 0; mi < 8; ++mi)
#pragma unroll
      for (int ni = 0; ni < 4; ++ni) {
        size_t r0 = (size_t)(m0 + wm * 128 + mi * 16 + g * 4);
        int cn = n0 + wn * 64 + ni * 16 + lr;
#pragma unroll
        for (int j = 0; j < 4; ++j) C[(r0 + j) * N + cn] = acc[mi][ni][j];
      }
  }
}

// ---------------------------------------------------------------- GEMM 128^2 (m97) for out-proj
template <int EPI>
__global__ void __launch_bounds__(256, 2)
gemm_bt(const u16* __restrict__ A, const u16* __restrict__ B,
        void* __restrict__ C0, void* __restrict__ C1, void* __restrict__ C2,
        int M, int N, int K, int MB) {
  __shared__ alignas(16) u16 sm[8192];
  const int tid = threadIdx.x;
  const int w = tid >> 6, lane = tid & 63;
  const int lr = lane & 15, g = lane >> 4;
  const int gb = (blockIdx.x & 7) * ((int)gridDim.x >> 3) + (blockIdx.x >> 3);
  const int mb = gb % MB, nb = gb / MB;
  const int m0 = mb * 128, n0 = nb * 128;

  const u16* src[4];
  u16* dst[4];
#pragma unroll
  for (int i = 0; i < 4; ++i) {
    int c = w * 4 + i;
    int r = (c & 7) * 16 + (lane >> 2);
    int sb = (lane & 3) ^ ((r >> 1) & 3);
    src[i] = (c < 8) ? (A + (size_t)(m0 + r) * K + sb * 8)
                     : (B + (size_t)(n0 + r) * K + sb * 8);
    dst[i] = &sm[c * 512];
  }

  f32x4 acc[4][4];
#pragma unroll
  for (int x = 0; x < 4; ++x)
#pragma unroll
    for (int y = 0; y < 4; ++y) acc[x][y] = f32x4{0.f, 0.f, 0.f, 0.f};

  const int rowb = (w >> 1) * 64, colb = (w & 1) * 64;
  const int nk = K >> 5;
  for (int kt = 0; kt < nk; ++kt) {
#pragma unroll
    for (int i = 0; i < 4; ++i) gload16(src[i] + kt * 32, dst[i]);
    __syncthreads();
    bf16x8 af[4], bfr[4];
#pragma unroll
    for (int mi = 0; mi < 4; ++mi) {
      int r = rowb + mi * 16 + lr;
      af[mi] = *(const bf16x8*)((const char*)sm + r * 64 +
                                ((g * 16) ^ (((r >> 1) & 3) << 4)));
    }
#pragma unroll
    for (int ni = 0; ni < 4; ++ni) {
      int r = colb + ni * 16 + lr;
      bfr[ni] = *(const bf16x8*)((const char*)sm + 8192 + r * 64 +
                                 ((g * 16) ^ (((r >> 1) & 3) << 4)));
    }
#pragma unroll
    for (int mi = 0; mi < 4; ++mi)
#pragma unroll
      for (int ni = 0; ni < 4; ++ni)
        acc[mi][ni] = MFMA(af[mi], bfr[ni], acc[mi][ni]);
    __syncthreads();
  }

  float* C = (float*)C0;
#pragma unroll
  for (int mi = 0; mi < 4; ++mi)
#pragma unroll
    for (int ni = 0; ni < 4; ++ni) {
      size_t r0 = (size_t)(m0 + rowb + mi * 16 + g * 4);
      int cn = n0 + colb + ni * 16 + lr;
#pragma unroll
      for (int j = 0; j < 4; ++j) C[(r0 + j) * N + cn] = acc[mi][ni][j];
    }
}

// ---------------------------------------------------------------- flash attention
// Split-KV, q=32/wave (proven 88-VGPR state): 8 waves / 512 thr. Waves 0-3 do
// kv[0,2048), waves 4-7 kv[2048,4096); wave (w&3) owns 32 q of the same 128-q
// block. Grid 512 = 2 blocks/CU = 4 waves/SIMD (2x the latency cover of R12).
// KV tile = 32 rows: K [32][256B] 4-bit-XOR; V quad-row [32][256B] (row j =
// d-rows 4j..4j+3, slot m holds (e<<2|b) = m^(j&15)) -> <=2-way aliasing (free).
// LDS 66KB: K g0/g1 dbuf 2x2x8KB @0, V g0/g1 dbuf @32768; merge region reuses it.
// End: waves 4-7 publish (O',m,l); waves 0-3 merge exactly (R6 math) and store.
__global__ void __launch_bounds__(512)
attn_kernel(const u16* __restrict__ qg, const u16* __restrict__ kg,
            const u16* __restrict__ vtg, u16* __restrict__ og) {
  __shared__ alignas(64) char smb[67584];
  const int tid = threadIdx.x;
  const int w = tid >> 6, lane = tid & 63;
  const int ql = lane & 31, hl = lane >> 5;
  const int gb = (blockIdx.x & 7) * 64 + (blockIdx.x >> 3);  // XCD swizzle (512=8*64)
  const int h = gb >> 5;
  const int qb = gb & 31;     // 128-q block
  const int g2 = w >> 2;      // kv half (compute)
  const int qw = w & 3;       // q chunk (32 rows)

  // staging roles: w0,1 K-g0 | w2,3 V-g0 | w4,5 K-g1 | w6,7 V-g1 (4 chunks each)
  const u16* ssrc[4];
  unsigned sdst[4];
  size_t sstep;
  {
    const int sg = w >> 2;
    if (!((w >> 1) & 1)) {  // K stager: tile [32 rows][256B]
      sstep = 32 * 128;
#pragma unroll
      for (int i = 0; i < 4; ++i) {
        int c = (w & 1) * 4 + i;
        int r = c * 4 + (lane >> 4);          // kv row 0..31
        int sb = (lane & 15) ^ (r & 15);      // 4-bit XOR (0 conflicts)
        ssrc[i] = kg + (size_t)(h * 4096 + sg * 2048 + r) * 128 + sb * 8;
        sdst[i] = sg * 16384 + c * 1024;
      }
    } else {                // V stager: quad-row tile [32 rows][256B]
      sstep = 32;
#pragma unroll
      for (int i = 0; i < 4; ++i) {
        int c = (w & 1) * 4 + i;
        int j = c * 4 + (lane >> 4);          // quad-row 0..31
        int x = (lane & 15) ^ (j & 15);
        int e = x >> 2, b = x & 3;
        ssrc[i] = vtg + (size_t)(h * 128 + 4 * j + e) * 4096 + sg * 2048 + b * 8;
        sdst[i] = 32768 + sg * 16384 + c * 1024;
      }
    }
  }

  // Q fragments, B-operand of 32x32x16: lane holds col q=ql, d-slice s = hl*8+(0..7)
  const u16* qrow = qg + (size_t)(h * 4096 + qb * 128 + qw * 32 + ql) * 128 + hl * 8;
  bf16x8 qf[8];
#pragma unroll
  for (int s = 0; s < 8; ++s) qf[s] = *(const bf16x8*)(qrow + s * 16);

  f32x16 of[4];
#pragma unroll
  for (int i = 0; i < 4; ++i)
#pragma unroll
    for (int r = 0; r < 16; ++r) of[i][r] = 0.f;
  float mrun = -1e30f, lsum = 0.f;
  const float thr = 6.0f;  // defer-max (exp2 domain)

  // prologue: stage tile 0 into buffer 0
#pragma unroll
  for (int i = 0; i < 4; ++i) gload16(ssrc[i], smb + sdst[i]);

  const int kxor = (ql & 15) << 4;
  const char* kbase = smb + g2 * 16384;
  const char* vbase = smb + 32768 + g2 * 16384;
  const int vj = ql >> 2;                 // quad-row within db-block
  const int vm0 = (ql & 3) << 2;          // e part of slot index

  for (int t = 0; t < 64; ++t) {
    const int cur = t & 1;
    asm volatile("s_waitcnt vmcnt(0)" ::: "memory");
    __builtin_amdgcn_s_barrier();
    FENCE;
    if (t + 1 < 64) {
      const int nb = (t + 1) & 1;
#pragma unroll
      for (int i = 0; i < 4; ++i)
        gload16(ssrc[i] + (size_t)(t + 1) * sstep, smb + sdst[i] + nb * 8192);
    }
    const char* kbuf = kbase + cur * 8192;
    const char* vbuf = vbase + cur * 8192;

    // S^T = K * Q^T over 32 kv (scores pre-scaled into exp2 domain via Q)
    f32x16 st0;
#pragma unroll
    for (int r = 0; r < 16; ++r) st0[r] = 0.f;
    __builtin_amdgcn_s_setprio(1);
#pragma unroll
    for (int s = 0; s < 8; ++s) {
      int off = ((s * 2 + hl) << 4) ^ kxor;
      bf16x8 k0 = *(const bf16x8*)(kbuf + ql * 256 + off);
      st0 = MFMA32(k0, qf[s], st0);
    }
    __builtin_amdgcn_s_setprio(0);

    // online softmax (exp2 domain), q = ql lane-local; lane^32 has complementary k
    float tmax = -1e30f;
#pragma unroll
    for (int r = 0; r < 16; ++r) tmax = fmaxf(tmax, st0[r]);
    tmax = fmaxf(tmax, __shfl_xor(tmax, 32));
    if (!__all(tmax - mrun <= thr)) {  // defer-max
      float mnew = fmaxf(mrun, tmax);
      float esc = EXP2(mrun - mnew);
#pragma unroll
      for (int db = 0; db < 4; ++db)
#pragma unroll
        for (int r = 0; r < 16; ++r) of[db][r] *= esc;
      lsum *= esc;
      mrun = mnew;
    }
    float psum = 0.f;
    unsigned pk0[8];
#pragma unroll
    for (int i = 0; i < 8; ++i) {
      float a0 = EXP2(st0[2 * i] - mrun);
      float b0 = EXP2(st0[2 * i + 1] - mrun);
      psum += a0 + b0;
      pk0[i] = cvtpk(a0, b0);
    }
    psum += __shfl_xor(psum, 32);
    lsum += psum;

    // P^T B-fragments in-register (16 bf16 per lane -> 2 kp fragments)
    pl32swap(pk0[0], pk0[2]); pl32swap(pk0[1], pk0[3]);
    pl32swap(pk0[4], pk0[6]); pl32swap(pk0[5], pk0[7]);
    union U { unsigned u[4]; bf16x8 v; };
    U paf[2];
#pragma unroll
    for (int i = 0; i < 4; ++i) { paf[0].u[i] = pk0[i]; paf[1].u[i] = pk0[4 + i]; }

    // O^T += Vt * P^T   (V quad-row layout)
    __builtin_amdgcn_s_setprio(1);
#pragma unroll
    for (int db = 0; db < 4; ++db) {
      int j = db * 8 + vj;
      const char* vrow = vbuf + j * 256;
#pragma unroll
      for (int kp = 0; kp < 2; ++kp) {
        int m = (vm0 | (kp * 2 + hl)) ^ (j & 15);
        bf16x8 vf = *(const bf16x8*)(vrow + m * 16);
        of[db] = MFMA32(vf, paf[kp].v, of[db]);
      }
    }
    __builtin_amdgcn_s_setprio(0);
    FENCE;
  }

  // ---- split-KV merge: waves 4-7 publish (O',m,l); waves 0-3 combine & store
  __syncthreads();
  if (w >= 4) {
    char* base = smb + qw * 16384 + lane * 256;
#pragma unroll
    for (int db = 0; db < 4; ++db) *(f32x16*)(base + db * 64) = of[db];
    float2 ml;
    ml.x = mrun; ml.y = lsum;
    *(float2*)(smb + 65536 + (qw * 64 + lane) * 8) = ml;
  }
  __syncthreads();
  if (w < 4) {
    const char* base = smb + qw * 16384 + lane * 256;
    float2 ml = *(const float2*)(smb + 65536 + (qw * 64 + lane) * 8);
    float m = fmaxf(mrun, ml.x);
    float a0 = EXP2(mrun - m);
    float a1 = EXP2(ml.x - m);
    float l = lsum * a0 + ml.y * a1;
    float linv = 1.f / (l + 1e-8f);
    float fa0 = a0 * linv, fa1 = a1 * linv;
    size_t qrow_o = (size_t)(qb * 128 + qw * 32 + ql) * 2048 + h * 128;
#pragma unroll
    for (int db = 0; db < 4; ++db) {
      f32x16 ob = *(const f32x16*)(base + db * 64);
#pragma unroll
      for (int u = 0; u < 4; ++u) {
        ushort4 pk;
        pk.x = f2bf(of[db][4 * u + 0] * fa0 + ob[4 * u + 0] * fa1);
        pk.y = f2bf(of[db][4 * u + 1] * fa0 + ob[4 * u + 1] * fa1);
        pk.z = f2bf(of[db][4 * u + 2] * fa0 + ob[4 * u + 2] * fa1);
        pk.w = f2bf(of[db][4 * u + 3] * fa0 + ob[4 * u + 3] * fa1);
        *(ushort4*)(og + qrow_o + db * 32 + 8 * u + hl * 4) = pk;
      }
    }
  }
}

// ---------------------------------------------------------------- launcher
extern "C" void kernel_launch(void* const* d_in, const int* in_sizes, int n_in,
                              void* d_out, int out_size, void* d_ws, size_t ws_size,
                              hipStream_t stream) {
  const float* x = (const float*)d_in[0];      // [4096][2048]
  const float* w_qkv = (const float*)d_in[1];  // [6144][2048]
  const float* w_out = (const float*)d_in[2];  // [2048][2048]

  char* ws = (char*)d_ws;
  u16* xb = (u16*)(ws + 0);            // 16 MB
  u16* wqkvb = (u16*)(ws + 16777216);  // 24 MB
  u16* woutb = (u16*)(ws + 41943040);  // 8 MB
  u16* qb = (u16*)(ws + 50331648);     // 16 MB  [NH][S][HD] (pre-scaled)
  u16* kb = (u16*)(ws + 67108864);     // 16 MB  [NH][S][HD]
  u16* vtb = (u16*)(ws + 83886080);    // 16 MB  [NH][HD][S]
  u16* aob = (u16*)(ws + 100663296);   // 16 MB  [S][H]

  cast_bf16<<<8192, 256, 0, stream>>>(x, xb, 2097152);
  cast_bf16<<<12288, 256, 0, stream>>>(w_qkv, wqkvb, 3145728);
  cast_bf16<<<4096, 256, 0, stream>>>(w_out, woutb, 1048576);

  gemm8<0><<<384, 512, 0, stream>>>(xb, wqkvb, qb, kb, vtb, 4096, 6144, 2048, 16);
  attn_kernel<<<512, 512, 0, stream>>>(qb, kb, vtb, aob);
  gemm_bt<1><<<32 * 16, 256, 0, stream>>>(aob, woutb, d_out, nullptr, nullptr, 4096, 2048, 2048, 32);
}

// Round 15
// 339.064 us; speedup vs baseline: 1.0679x; 1.0679x over previous
//
#include <hip/hip_runtime.h>
#include <stdint.h>

typedef __attribute__((ext_vector_type(4))) float f32x4;
typedef __attribute__((ext_vector_type(16))) float f32x16;
typedef __attribute__((ext_vector_type(8))) short bf16x8;
typedef unsigned short u16;

#define MFMA(a, b, c) __builtin_amdgcn_mfma_f32_16x16x32_bf16(a, b, c, 0, 0, 0)
#define MFMA32(a, b, c) __builtin_amdgcn_mfma_f32_32x32x16_bf16(a, b, c, 0, 0, 0)
#define EXP2(x) __builtin_amdgcn_exp2f(x)
#define FENCE asm volatile("" ::: "memory")
#define BARRIER do { FENCE; __builtin_amdgcn_s_barrier(); FENCE; } while (0)

__device__ __forceinline__ u16 f2bf(float f) {
  union { float f; unsigned u; } x; x.f = f;
  unsigned r = x.u + 0x7fffu + ((x.u >> 16) & 1u);
  return (u16)(r >> 16);
}

__device__ __forceinline__ unsigned cvtpk(float lo, float hi) {
  unsigned r;
  asm("v_cvt_pk_bf16_f32 %0, %1, %2" : "=v"(r) : "v"(lo), "v"(hi));
  return r;
}

__device__ __forceinline__ void pl32swap(unsigned& a, unsigned& b) {
  asm volatile("v_permlane32_swap_b32 %0, %1" : "+v"(a), "+v"(b));
}

__device__ __forceinline__ void gload16(const void* g, void* l) {
  __builtin_amdgcn_global_load_lds(
      (const __attribute__((address_space(1))) unsigned int*)g,
      (__attribute__((address_space(3))) unsigned int*)l, 16, 0, 0);
}

// ---------------------------------------------------------------- cast f32->bf16
__global__ void __launch_bounds__(256) cast_bf16(const float* __restrict__ in,
                                                 u16* __restrict__ out, int n4) {
  int i = blockIdx.x * 256 + threadIdx.x;
  if (i >= n4) return;
  float4 v = reinterpret_cast<const float4*>(in)[i];
  ushort4 o;
  o.x = f2bf(v.x); o.y = f2bf(v.y); o.z = f2bf(v.z); o.w = f2bf(v.w);
  reinterpret_cast<ushort4*>(out)[i] = o;
}

// ---------------------------------------------------------------- 8-phase 256^2 GEMM
// (R11 structure, proven). EPI 0: q/k/v_t scatter (Q pre-scaled); EPI 1: float C.
template <int EPI>
__global__ void __launch_bounds__(512)
gemm8(const u16* __restrict__ A, const u16* __restrict__ B,
      void* __restrict__ C0, void* __restrict__ C1, void* __restrict__ C2,
      int M, int N, int K, int MBt) {
  __shared__ alignas(16) char smb[131072];
  const int tid = threadIdx.x;
  const int w = tid >> 6, lane = tid & 63;
  const int lr = lane & 15, g = lane >> 4;
  const int wm = w >> 2, wn = w & 3;
  const int gb = (blockIdx.x & 7) * ((int)gridDim.x >> 3) + (blockIdx.x >> 3);
  const int mb = gb % MBt, nb = gb / MBt;
  const int m0 = mb * 256, n0 = nb * 256;
  const int NT = K >> 6, NIT = NT >> 1;

  const int l8 = lane >> 3, l7 = lane & 7;
  const int csb = (l7 ^ l8) * 16;
  const char* asrcb[2];
  const char* bsrcb[2];
  unsigned adst[2], bdst[2];
#pragma unroll
  for (int j = 0; j < 2; ++j) {
    int c = 2 * w + j;
    int ra = (c & 7) * 8 + ((c >> 3) << 7) + l8;
    asrcb[j] = (const char*)(A + (size_t)(m0 + ra) * K) + csb;
    adst[j] = (unsigned)(ra * 128 + l7 * 16);
    int rb = (c & 3) * 8 + ((c >> 2) << 6) + l8;
    bsrcb[j] = (const char*)(B + (size_t)(n0 + rb) * K) + csb;
    bdst[j] = (unsigned)(rb * 128 + l7 * 16);
  }
  const size_t arow64 = (size_t)64 * K * 2;
  const size_t brow32 = (size_t)32 * K * 2;

#define STG(kt, u)                                                            \
  do {                                                                        \
    if ((kt) < NT) {                                                          \
      int _d = ((kt) & 1) ? 32768 : 0;                                        \
      size_t _ko = (size_t)(kt) * 128;                                        \
      if ((u) == 0) {                                                         \
        gload16(asrcb[0] + _ko, smb + _d + adst[0]);                          \
        gload16(asrcb[1] + _ko, smb + _d + adst[1]);                          \
      } else if ((u) == 1) {                                                  \
        gload16(bsrcb[0] + _ko, smb + 65536 + _d + bdst[0]);                  \
        gload16(bsrcb[1] + _ko, smb + 65536 + _d + bdst[1]);                  \
      } else if ((u) == 2) {                                                  \
        gload16(asrcb[0] + arow64 + _ko, smb + _d + 8192 + adst[0]);          \
        gload16(asrcb[1] + arow64 + _ko, smb + _d + 8192 + adst[1]);          \
      } else {                                                                \
        gload16(bsrcb[0] + brow32 + _ko, smb + 65536 + _d + 4096 + bdst[0]);  \
        gload16(bsrcb[1] + brow32 + _ko, smb + 65536 + _d + 4096 + bdst[1]);  \
      }                                                                       \
    }                                                                         \
  } while (0)

  f32x4 acc[8][4];
#pragma unroll
  for (int x = 0; x < 8; ++x)
#pragma unroll
    for (int y = 0; y < 4; ++y) acc[x][y] = f32x4{0.f, 0.f, 0.f, 0.f};
  bf16x8 af[4][2], bf01[2][2], bf23[2][2];
  const int aoff0 = ((g) ^ (lr & 7)) << 4;
  const int aoff1 = ((4 + g) ^ (lr & 7)) << 4;
  const int arow = (wm * 128 + lr) * 128;
  const int brow = (wn * 64 + lr) * 128;

  auto LDA = [&](const char* base, int mih) {
#pragma unroll
    for (int mi = 0; mi < 4; ++mi) {
      const char* p = base + arow + (mih * 64 + mi * 16) * 128;
      af[mi][0] = *(const bf16x8*)(p + aoff0);
      af[mi][1] = *(const bf16x8*)(p + aoff1);
    }
  };
  auto LDB = [&](const char* base, bf16x8 (*bfr)[2], int nih) {
#pragma unroll
    for (int ni = 0; ni < 2; ++ni) {
      const char* p = base + brow + (nih * 32 + ni * 16) * 128;
      bfr[ni][0] = *(const bf16x8*)(p + aoff0);
      bfr[ni][1] = *(const bf16x8*)(p + aoff1);
    }
  };
  auto MM = [&](int mih, int nih, bf16x8 (*bfr)[2]) {
    __builtin_amdgcn_s_setprio(1);
#pragma unroll
    for (int mi = 0; mi < 4; ++mi)
#pragma unroll
      for (int ni = 0; ni < 2; ++ni) {
        acc[mih * 4 + mi][nih * 2 + ni] =
            MFMA(af[mi][0], bfr[ni][0], acc[mih * 4 + mi][nih * 2 + ni]);
        acc[mih * 4 + mi][nih * 2 + ni] =
            MFMA(af[mi][1], bfr[ni][1], acc[mih * 4 + mi][nih * 2 + ni]);
      }
    __builtin_amdgcn_s_setprio(0);
  };

  STG(0, 0); STG(0, 1); STG(0, 2); STG(0, 3);
  STG(1, 0); STG(1, 1); STG(1, 2);
  asm volatile("s_waitcnt vmcnt(6)" ::: "memory");
  BARRIER;

  const char* A0 = smb;
  const char* B0 = smb + 65536;
  const char* A1 = smb + 32768;
  const char* B1 = smb + 65536 + 32768;

  for (int it = 0; it < NIT; ++it) {
    const int t0 = 2 * it;
    const bool lastit = (it == NIT - 1);
    LDA(A0, 0); LDB(B0, bf01, 0); STG(t0 + 1, 3);
    BARRIER; MM(0, 0, bf01); BARRIER;
    LDB(B0, bf23, 1); STG(t0 + 2, 0);
    BARRIER; MM(0, 1, bf23); BARRIER;
    LDA(A0, 1); STG(t0 + 2, 1);
    BARRIER; MM(1, 1, bf23); BARRIER;
    STG(t0 + 2, 2);
    if (lastit) asm volatile("s_waitcnt vmcnt(0)" ::: "memory");
    else        asm volatile("s_waitcnt vmcnt(6)" ::: "memory");
    BARRIER; MM(1, 0, bf01); BARRIER;
    LDA(A1, 0); LDB(B1, bf01, 0); STG(t0 + 2, 3);
    BARRIER; MM(0, 0, bf01); BARRIER;
    LDB(B1, bf23, 1); STG(t0 + 3, 0);
    BARRIER; MM(0, 1, bf23); BARRIER;
    LDA(A1, 1); STG(t0 + 3, 1);
    BARRIER; MM(1, 1, bf23); BARRIER;
    STG(t0 + 3, 2);
    asm volatile("s_waitcnt vmcnt(6)" ::: "memory");
    BARRIER; MM(1, 0, bf01); BARRIER;
  }
#undef STG

  if (EPI == 0) {
    const float qs = 0.08838834764831845f * 1.4426950408889634f;
    u16* qo = (u16*)C0;
    u16* ko = (u16*)C1;
    u16* vo = (u16*)C2;
#pragma unroll
    for (int mi = 0; mi < 8; ++mi) {
      int s0 = m0 + wm * 128 + mi * 16 + g * 4;
#pragma unroll
      for (int ni = 0; ni < 4; ++ni) {
        int n = n0 + wn * 64 + ni * 16 + lr;
        int t = n >> 11, hh = (n >> 7) & 15, d = n & 127;
        if (t == 2) {
          ushort4 pk;
          pk.x = f2bf(acc[mi][ni][0]);
          pk.y = f2bf(acc[mi][ni][1]);
          pk.z = f2bf(acc[mi][ni][2]);
          pk.w = f2bf(acc[mi][ni][3]);
          *(ushort4*)(vo + (size_t)(hh * 128 + d) * 4096 + s0) = pk;
        } else {
          float sc = (t == 0) ? qs : 1.f;
          u16* dq = (t == 0 ? qo : ko) + (size_t)(hh * 4096 + s0) * 128 + d;
#pragma unroll
          for (int j = 0; j < 4; ++j) dq[(size_t)j * 128] = f2bf(acc[mi][ni][j] * sc);
        }
      }
    }
  } else {
    float* C = (float*)C0;
#pragma unroll
    for (int mi = 0; mi < 8; ++mi)
#pragma unroll
      for (int ni = 0; ni < 4; ++ni) {
        size_t r0 = (size_t)(m0 + wm * 128 + mi * 16 + g * 4);
        int cn = n0 + wn * 64 + ni * 16 + lr;
#pragma unroll
        for (int j = 0; j < 4; ++j) C[(r0 + j) * N + cn] = acc[mi][ni][j];
      }
  }
}

// ---------------------------------------------------------------- flash attention
// R12 structure (proven 166.7us: 8 waves / 512 thr, grid 256 = 1 block/CU,
// q=32/wave, in-register P, O^T accumulate, zero-conflict XOR LDS, defer-max,
// setprio, XCD swizzle) with KVBLK 64 -> 128: 32 iters instead of 64, halving
// per-iter fixed costs (barrier drain, softmax reduce/branch, O-rescale) at
// constant per-kv LDS traffic. V rows are now naturally 256B -> same 4-bit-XOR
// class as K (pair-row trick gone). LDS: K dbuf 2x32KB @0, V dbuf 2x32KB @64KB.
__global__ void __launch_bounds__(512)
attn_kernel(const u16* __restrict__ qg, const u16* __restrict__ kg,
            const u16* __restrict__ vtg, u16* __restrict__ og) {
  __shared__ alignas(64) char smb[131072];
  const int tid = threadIdx.x;
  const int w = tid >> 6, lane = tid & 63;
  const int ql = lane & 31, hl = lane >> 5;
  const int gb = (blockIdx.x & 7) * 32 + (blockIdx.x >> 3);  // XCD swizzle (256=8*32)
  const int h = gb >> 4;
  const int qb = gb & 15;

  // staging: waves 0-3 -> K tile [128][256B] (chunks w*8..w*8+7),
  //          waves 4-7 -> V tile [128 d][256B] (chunks (w-4)*8..+7).
  // Both tiles: LDS slot m of row r holds source 16B-block m^(r&15).
  const u16* ssrc[8];
  unsigned sdst[8];
  size_t sstep;
  if (w < 4) {
    sstep = 128 * 128;  // next 128 kv rows
#pragma unroll
    for (int i = 0; i < 8; ++i) {
      int c = w * 8 + i;
      int r = c * 4 + (lane >> 4);           // kv row 0..127
      int sb = (lane & 15) ^ (r & 15);
      ssrc[i] = kg + (size_t)(h * 4096 + r) * 128 + sb * 8;
      sdst[i] = c * 1024;
    }
  } else {
    sstep = 128;  // next 128 kv columns of v_t
#pragma unroll
    for (int i = 0; i < 8; ++i) {
      int c = (w - 4) * 8 + i;
      int r = c * 4 + (lane >> 4);           // d row 0..127
      int sb = (lane & 15) ^ (r & 15);
      ssrc[i] = vtg + (size_t)(h * 128 + r) * 4096 + sb * 8;
      sdst[i] = 65536 + c * 1024;
    }
  }

  // Q fragments, B-operand of 32x32x16: lane holds col q=ql, d-slice s = hl*8+(0..7)
  const u16* qrow = qg + (size_t)(h * 4096 + qb * 256 + w * 32 + ql) * 128 + hl * 8;
  bf16x8 qf[8];
#pragma unroll
  for (int s = 0; s < 8; ++s) qf[s] = *(const bf16x8*)(qrow + s * 16);

  f32x16 of[4];
#pragma unroll
  for (int i = 0; i < 4; ++i)
#pragma unroll
    for (int r = 0; r < 16; ++r) of[i][r] = 0.f;
  float mrun = -1e30f, lsum = 0.f;
  const float thr = 6.0f;  // defer-max (exp2 domain)

  // prologue: stage tile 0 into buffer 0
#pragma unroll
  for (int i = 0; i < 8; ++i) gload16(ssrc[i], smb + sdst[i]);

  const int kxor = (ql & 15) << 4;
  for (int t = 0; t < 32; ++t) {
    const int cur = t & 1;
    asm volatile("s_waitcnt vmcnt(0)" ::: "memory");
    __builtin_amdgcn_s_barrier();
    FENCE;
    if (t + 1 < 32) {
      const int nb = (t + 1) & 1;
#pragma unroll
      for (int i = 0; i < 8; ++i)
        gload16(ssrc[i] + (size_t)(t + 1) * sstep, smb + sdst[i] + nb * 32768);
    }
    const char* kbuf = smb + cur * 32768;
    const char* vbuf = smb + 65536 + cur * 32768;

    // S^T = K * Q^T over 128 kv (scores pre-scaled into exp2 domain via Q)
    f32x16 st[4];
#pragma unroll
    for (int kb = 0; kb < 4; ++kb)
#pragma unroll
      for (int r = 0; r < 16; ++r) st[kb][r] = 0.f;
    __builtin_amdgcn_s_setprio(1);
#pragma unroll
    for (int s = 0; s < 8; ++s) {
      int off = ((s * 2 + hl) << 4) ^ kxor;
      bf16x8 k0 = *(const bf16x8*)(kbuf + (0 * 32 + ql) * 256 + off);
      bf16x8 k1 = *(const bf16x8*)(kbuf + (1 * 32 + ql) * 256 + off);
      bf16x8 k2 = *(const bf16x8*)(kbuf + (2 * 32 + ql) * 256 + off);
      bf16x8 k3 = *(const bf16x8*)(kbuf + (3 * 32 + ql) * 256 + off);
      st[0] = MFMA32(k0, qf[s], st[0]);
      st[1] = MFMA32(k1, qf[s], st[1]);
      st[2] = MFMA32(k2, qf[s], st[2]);
      st[3] = MFMA32(k3, qf[s], st[3]);
    }
    __builtin_amdgcn_s_setprio(0);

    // online softmax (exp2 domain), q = ql lane-local; lane^32 has complementary k
    float tmax = -1e30f;
#pragma unroll
    for (int kb = 0; kb < 4; ++kb)
#pragma unroll
      for (int r = 0; r < 16; ++r) tmax = fmaxf(tmax, st[kb][r]);
    tmax = fmaxf(tmax, __shfl_xor(tmax, 32));
    if (!__all(tmax - mrun <= thr)) {  // defer-max
      float mnew = fmaxf(mrun, tmax);
      float esc = EXP2(mrun - mnew);
#pragma unroll
      for (int db = 0; db < 4; ++db)
#pragma unroll
        for (int r = 0; r < 16; ++r) of[db][r] *= esc;
      lsum *= esc;
      mrun = mnew;
    }
    float psum = 0.f;
    union U { unsigned u[4]; bf16x8 v; };
    U paf[8];
#pragma unroll
    for (int gp = 0; gp < 2; ++gp) {  // gp: kv halves 0..63 / 64..127
      unsigned pk0[8], pk1[8];
#pragma unroll
      for (int i = 0; i < 8; ++i) {
        float a0 = EXP2(st[2 * gp + 0][2 * i] - mrun);
        float b0 = EXP2(st[2 * gp + 0][2 * i + 1] - mrun);
        float a1 = EXP2(st[2 * gp + 1][2 * i] - mrun);
        float b1 = EXP2(st[2 * gp + 1][2 * i + 1] - mrun);
        psum += (a0 + b0) + (a1 + b1);
        pk0[i] = cvtpk(a0, b0);
        pk1[i] = cvtpk(a1, b1);
      }
      pl32swap(pk0[0], pk0[2]); pl32swap(pk0[1], pk0[3]);
      pl32swap(pk0[4], pk0[6]); pl32swap(pk0[5], pk0[7]);
      pl32swap(pk1[0], pk1[2]); pl32swap(pk1[1], pk1[3]);
      pl32swap(pk1[4], pk1[6]); pl32swap(pk1[5], pk1[7]);
#pragma unroll
      for (int i = 0; i < 4; ++i) {
        paf[gp * 4 + 0].u[i] = pk0[i];
        paf[gp * 4 + 1].u[i] = pk0[4 + i];
        paf[gp * 4 + 2].u[i] = pk1[i];
        paf[gp * 4 + 3].u[i] = pk1[4 + i];
      }
    }
    psum += __shfl_xor(psum, 32);
    lsum += psum;

    // O^T += Vt * P^T  (V [128 d][256B], same XOR class as K)
    __builtin_amdgcn_s_setprio(1);
#pragma unroll
    for (int db = 0; db < 4; ++db) {
      const char* vrow = vbuf + (db * 32 + ql) * 256;
#pragma unroll
      for (int kp = 0; kp < 8; ++kp) {
        int m = (kp * 2 + hl) ^ (ql & 15);
        bf16x8 vf = *(const bf16x8*)(vrow + m * 16);
        of[db] = MFMA32(vf, paf[kp].v, of[db]);
      }
    }
    __builtin_amdgcn_s_setprio(0);
    FENCE;
  }

  // epilogue: lane owns q = ql; d = db*32 + (r&3) + 8*(r>>2) + 4*hl
  float linv = 1.f / (lsum + 1e-8f);
  size_t qrow_o = (size_t)(qb * 256 + w * 32 + ql) * 2048 + h * 128;
#pragma unroll
  for (int db = 0; db < 4; ++db)
#pragma unroll
    for (int u = 0; u < 4; ++u) {
      ushort4 pk;
      pk.x = f2bf(of[db][4 * u + 0] * linv);
      pk.y = f2bf(of[db][4 * u + 1] * linv);
      pk.z = f2bf(of[db][4 * u + 2] * linv);
      pk.w = f2bf(of[db][4 * u + 3] * linv);
      *(ushort4*)(og + qrow_o + db * 32 + 8 * u + hl * 4) = pk;
    }
}

// ---------------------------------------------------------------- launcher
extern "C" void kernel_launch(void* const* d_in, const int* in_sizes, int n_in,
                              void* d_out, int out_size, void* d_ws, size_t ws_size,
                              hipStream_t stream) {
  const float* x = (const float*)d_in[0];      // [4096][2048]
  const float* w_qkv = (const float*)d_in[1];  // [6144][2048]
  const float* w_out = (const float*)d_in[2];  // [2048][2048]

  char* ws = (char*)d_ws;
  u16* xb = (u16*)(ws + 0);            // 16 MB
  u16* wqkvb = (u16*)(ws + 16777216);  // 24 MB
  u16* woutb = (u16*)(ws + 41943040);  // 8 MB
  u16* qb = (u16*)(ws + 50331648);     // 16 MB  [NH][S][HD] (pre-scaled)
  u16* kb = (u16*)(ws + 67108864);     // 16 MB  [NH][S][HD]
  u16* vtb = (u16*)(ws + 83886080);    // 16 MB  [NH][HD][S]
  u16* aob = (u16*)(ws + 100663296);   // 16 MB  [S][H]

  cast_bf16<<<8192, 256, 0, stream>>>(x, xb, 2097152);
  cast_bf16<<<12288, 256, 0, stream>>>(w_qkv, wqkvb, 3145728);
  cast_bf16<<<4096, 256, 0, stream>>>(w_out, woutb, 1048576);

  gemm8<0><<<384, 512, 0, stream>>>(xb, wqkvb, qb, kb, vtb, 4096, 6144, 2048, 16);
  attn_kernel<<<256, 512, 0, stream>>>(qb, kb, vtb, aob);
  gemm8<1><<<128, 512, 0, stream>>>(aob, woutb, d_out, nullptr, nullptr, 4096, 2048, 2048, 16);
}

// Round 16
// 330.391 us; speedup vs baseline: 1.0960x; 1.0263x over previous
//
#include <hip/hip_runtime.h>
#include <stdint.h>

typedef __attribute__((ext_vector_type(4))) float f32x4;
typedef __attribute__((ext_vector_type(16))) float f32x16;
typedef __attribute__((ext_vector_type(8))) short bf16x8;
typedef unsigned short u16;

#define MFMA(a, b, c) __builtin_amdgcn_mfma_f32_16x16x32_bf16(a, b, c, 0, 0, 0)
#define MFMA32(a, b, c) __builtin_amdgcn_mfma_f32_32x32x16_bf16(a, b, c, 0, 0, 0)
#define EXP2(x) __builtin_amdgcn_exp2f(x)
#define FENCE asm volatile("" ::: "memory")
#define BARRIER do { FENCE; __builtin_amdgcn_s_barrier(); FENCE; } while (0)

__device__ __forceinline__ u16 f2bf(float f) {
  union { float f; unsigned u; } x; x.f = f;
  unsigned r = x.u + 0x7fffu + ((x.u >> 16) & 1u);
  return (u16)(r >> 16);
}

__device__ __forceinline__ unsigned cvtpk(float lo, float hi) {
  unsigned r;
  asm("v_cvt_pk_bf16_f32 %0, %1, %2" : "=v"(r) : "v"(lo), "v"(hi));
  return r;
}

__device__ __forceinline__ void pl32swap(unsigned& a, unsigned& b) {
  asm volatile("v_permlane32_swap_b32 %0, %1" : "+v"(a), "+v"(b));
}

__device__ __forceinline__ void gload16(const void* g, void* l) {
  __builtin_amdgcn_global_load_lds(
      (const __attribute__((address_space(1))) unsigned int*)g,
      (__attribute__((address_space(3))) unsigned int*)l, 16, 0, 0);
}

// ---------------------------------------------------------------- cast f32->bf16
__global__ void __launch_bounds__(256) cast_bf16(const float* __restrict__ in,
                                                 u16* __restrict__ out, int n4) {
  int i = blockIdx.x * 256 + threadIdx.x;
  if (i >= n4) return;
  float4 v = reinterpret_cast<const float4*>(in)[i];
  ushort4 o;
  o.x = f2bf(v.x); o.y = f2bf(v.y); o.z = f2bf(v.z); o.w = f2bf(v.w);
  reinterpret_cast<ushort4*>(out)[i] = o;
}

// ---------------------------------------------------------------- 8-phase 256^2 GEMM (QKV)
template <int EPI>
__global__ void __launch_bounds__(512)
gemm8(const u16* __restrict__ A, const u16* __restrict__ B,
      void* __restrict__ C0, void* __restrict__ C1, void* __restrict__ C2,
      int M, int N, int K, int MBt) {
  __shared__ alignas(16) char smb[131072];
  const int tid = threadIdx.x;
  const int w = tid >> 6, lane = tid & 63;
  const int lr = lane & 15, g = lane >> 4;
  const int wm = w >> 2, wn = w & 3;
  const int gb = (blockIdx.x & 7) * ((int)gridDim.x >> 3) + (blockIdx.x >> 3);
  const int mb = gb % MBt, nb = gb / MBt;
  const int m0 = mb * 256, n0 = nb * 256;
  const int NT = K >> 6, NIT = NT >> 1;

  const int l8 = lane >> 3, l7 = lane & 7;
  const int csb = (l7 ^ l8) * 16;
  const char* asrcb[2];
  const char* bsrcb[2];
  unsigned adst[2], bdst[2];
#pragma unroll
  for (int j = 0; j < 2; ++j) {
    int c = 2 * w + j;
    int ra = (c & 7) * 8 + ((c >> 3) << 7) + l8;
    asrcb[j] = (const char*)(A + (size_t)(m0 + ra) * K) + csb;
    adst[j] = (unsigned)(ra * 128 + l7 * 16);
    int rb = (c & 3) * 8 + ((c >> 2) << 6) + l8;
    bsrcb[j] = (const char*)(B + (size_t)(n0 + rb) * K) + csb;
    bdst[j] = (unsigned)(rb * 128 + l7 * 16);
  }
  const size_t arow64 = (size_t)64 * K * 2;
  const size_t brow32 = (size_t)32 * K * 2;

#define STG(kt, u)                                                            \
  do {                                                                        \
    if ((kt) < NT) {                                                          \
      int _d = ((kt) & 1) ? 32768 : 0;                                        \
      size_t _ko = (size_t)(kt) * 128;                                        \
      if ((u) == 0) {                                                         \
        gload16(asrcb[0] + _ko, smb + _d + adst[0]);                          \
        gload16(asrcb[1] + _ko, smb + _d + adst[1]);                          \
      } else if ((u) == 1) {                                                  \
        gload16(bsrcb[0] + _ko, smb + 65536 + _d + bdst[0]);                  \
        gload16(bsrcb[1] + _ko, smb + 65536 + _d + bdst[1]);                  \
      } else if ((u) == 2) {                                                  \
        gload16(asrcb[0] + arow64 + _ko, smb + _d + 8192 + adst[0]);          \
        gload16(asrcb[1] + arow64 + _ko, smb + _d + 8192 + adst[1]);          \
      } else {                                                                \
        gload16(bsrcb[0] + brow32 + _ko, smb + 65536 + _d + 4096 + bdst[0]);  \
        gload16(bsrcb[1] + brow32 + _ko, smb + 65536 + _d + 4096 + bdst[1]);  \
      }                                                                       \
    }                                                                         \
  } while (0)

  f32x4 acc[8][4];
#pragma unroll
  for (int x = 0; x < 8; ++x)
#pragma unroll
    for (int y = 0; y < 4; ++y) acc[x][y] = f32x4{0.f, 0.f, 0.f, 0.f};
  bf16x8 af[4][2], bf01[2][2], bf23[2][2];
  const int aoff0 = ((g) ^ (lr & 7)) << 4;
  const int aoff1 = ((4 + g) ^ (lr & 7)) << 4;
  const int arow = (wm * 128 + lr) * 128;
  const int brow = (wn * 64 + lr) * 128;

  auto LDA = [&](const char* base, int mih) {
#pragma unroll
    for (int mi = 0; mi < 4; ++mi) {
      const char* p = base + arow + (mih * 64 + mi * 16) * 128;
      af[mi][0] = *(const bf16x8*)(p + aoff0);
      af[mi][1] = *(const bf16x8*)(p + aoff1);
    }
  };
  auto LDB = [&](const char* base, bf16x8 (*bfr)[2], int nih) {
#pragma unroll
    for (int ni = 0; ni < 2; ++ni) {
      const char* p = base + brow + (nih * 32 + ni * 16) * 128;
      bfr[ni][0] = *(const bf16x8*)(p + aoff0);
      bfr[ni][1] = *(const bf16x8*)(p + aoff1);
    }
  };
  auto MM = [&](int mih, int nih, bf16x8 (*bfr)[2]) {
    __builtin_amdgcn_s_setprio(1);
#pragma unroll
    for (int mi = 0; mi < 4; ++mi)
#pragma unroll
      for (int ni = 0; ni < 2; ++ni) {
        acc[mih * 4 + mi][nih * 2 + ni] =
            MFMA(af[mi][0], bfr[ni][0], acc[mih * 4 + mi][nih * 2 + ni]);
        acc[mih * 4 + mi][nih * 2 + ni] =
            MFMA(af[mi][1], bfr[ni][1], acc[mih * 4 + mi][nih * 2 + ni]);
      }
    __builtin_amdgcn_s_setprio(0);
  };

  STG(0, 0); STG(0, 1); STG(0, 2); STG(0, 3);
  STG(1, 0); STG(1, 1); STG(1, 2);
  asm volatile("s_waitcnt vmcnt(6)" ::: "memory");
  BARRIER;

  const char* A0 = smb;
  const char* B0 = smb + 65536;
  const char* A1 = smb + 32768;
  const char* B1 = smb + 65536 + 32768;

  for (int it = 0; it < NIT; ++it) {
    const int t0 = 2 * it;
    const bool lastit = (it == NIT - 1);
    LDA(A0, 0); LDB(B0, bf01, 0); STG(t0 + 1, 3);
    BARRIER; MM(0, 0, bf01); BARRIER;
    LDB(B0, bf23, 1); STG(t0 + 2, 0);
    BARRIER; MM(0, 1, bf23); BARRIER;
    LDA(A0, 1); STG(t0 + 2, 1);
    BARRIER; MM(1, 1, bf23); BARRIER;
    STG(t0 + 2, 2);
    if (lastit) asm volatile("s_waitcnt vmcnt(0)" ::: "memory");
    else        asm volatile("s_waitcnt vmcnt(6)" ::: "memory");
    BARRIER; MM(1, 0, bf01); BARRIER;
    LDA(A1, 0); LDB(B1, bf01, 0); STG(t0 + 2, 3);
    BARRIER; MM(0, 0, bf01); BARRIER;
    LDB(B1, bf23, 1); STG(t0 + 3, 0);
    BARRIER; MM(0, 1, bf23); BARRIER;
    LDA(A1, 1); STG(t0 + 3, 1);
    BARRIER; MM(1, 1, bf23); BARRIER;
    STG(t0 + 3, 2);
    asm volatile("s_waitcnt vmcnt(6)" ::: "memory");
    BARRIER; MM(1, 0, bf01); BARRIER;
  }
#undef STG

  if (EPI == 0) {
    const float qs = 0.08838834764831845f * 1.4426950408889634f;
    u16* qo = (u16*)C0;
    u16* ko = (u16*)C1;
    u16* vo = (u16*)C2;
#pragma unroll
    for (int mi = 0; mi < 8; ++mi) {
      int s0 = m0 + wm * 128 + mi * 16 + g * 4;
#pragma unroll
      for (int ni = 0; ni < 4; ++ni) {
        int n = n0 + wn * 64 + ni * 16 + lr;
        int t = n >> 11, hh = (n >> 7) & 15, d = n & 127;
        if (t == 2) {
          ushort4 pk;
          pk.x = f2bf(acc[mi][ni][0]);
          pk.y = f2bf(acc[mi][ni][1]);
          pk.z = f2bf(acc[mi][ni][2]);
          pk.w = f2bf(acc[mi][ni][3]);
          *(ushort4*)(vo + (size_t)(hh * 128 + d) * 4096 + s0) = pk;
        } else {
          float sc = (t == 0) ? qs : 1.f;
          u16* dq = (t == 0 ? qo : ko) + (size_t)(hh * 4096 + s0) * 128 + d;
#pragma unroll
          for (int j = 0; j < 4; ++j) dq[(size_t)j * 128] = f2bf(acc[mi][ni][j] * sc);
        }
      }
    }
  } else {
    float* C = (float*)C0;
#pragma unroll
    for (int mi = 0; mi < 8; ++mi)
#pragma unroll
      for (int ni = 0; ni < 4; ++ni) {
        size_t r0 = (size_t)(m0 + wm * 128 + mi * 16 + g * 4);
        int cn = n0 + wn * 64 + ni * 16 + lr;
#pragma unroll
        for (int j = 0; j < 4; ++j) C[(r0 + j) * N + cn] = acc[mi][ni][j];
      }
  }
}

// ---------------------------------------------------------------- GEMM 128^2 (m97) for out-proj
template <int EPI>
__global__ void __launch_bounds__(256, 2)
gemm_bt(const u16* __restrict__ A, const u16* __restrict__ B,
        void* __restrict__ C0, void* __restrict__ C1, void* __restrict__ C2,
        int M, int N, int K, int MB) {
  __shared__ alignas(16) u16 sm[8192];
  const int tid = threadIdx.x;
  const int w = tid >> 6, lane = tid & 63;
  const int lr = lane & 15, g = lane >> 4;
  const int gb = (blockIdx.x & 7) * ((int)gridDim.x >> 3) + (blockIdx.x >> 3);
  const int mb = gb % MB, nb = gb / MB;
  const int m0 = mb * 128, n0 = nb * 128;

  const u16* src[4];
  u16* dst[4];
#pragma unroll
  for (int i = 0; i < 4; ++i) {
    int c = w * 4 + i;
    int r = (c & 7) * 16 + (lane >> 2);
    int sb = (lane & 3) ^ ((r >> 1) & 3);
    src[i] = (c < 8) ? (A + (size_t)(m0 + r) * K + sb * 8)
                     : (B + (size_t)(n0 + r) * K + sb * 8);
    dst[i] = &sm[c * 512];
  }

  f32x4 acc[4][4];
#pragma unroll
  for (int x = 0; x < 4; ++x)
#pragma unroll
    for (int y = 0; y < 4; ++y) acc[x][y] = f32x4{0.f, 0.f, 0.f, 0.f};

  const int rowb = (w >> 1) * 64, colb = (w & 1) * 64;
  const int nk = K >> 5;
  for (int kt = 0; kt < nk; ++kt) {
#pragma unroll
    for (int i = 0; i < 4; ++i) gload16(src[i] + kt * 32, dst[i]);
    __syncthreads();
    bf16x8 af[4], bfr[4];
#pragma unroll
    for (int mi = 0; mi < 4; ++mi) {
      int r = rowb + mi * 16 + lr;
      af[mi] = *(const bf16x8*)((const char*)sm + r * 64 +
                                ((g * 16) ^ (((r >> 1) & 3) << 4)));
    }
#pragma unroll
    for (int ni = 0; ni < 4; ++ni) {
      int r = colb + ni * 16 + lr;
      bfr[ni] = *(const bf16x8*)((const char*)sm + 8192 + r * 64 +
                                 ((g * 16) ^ (((r >> 1) & 3) << 4)));
    }
#pragma unroll
    for (int mi = 0; mi < 4; ++mi)
#pragma unroll
      for (int ni = 0; ni < 4; ++ni)
        acc[mi][ni] = MFMA(af[mi], bfr[ni], acc[mi][ni]);
    __syncthreads();
  }

  float* C = (float*)C0;
#pragma unroll
  for (int mi = 0; mi < 4; ++mi)
#pragma unroll
    for (int ni = 0; ni < 4; ++ni) {
      size_t r0 = (size_t)(m0 + rowb + mi * 16 + g * 4);
      int cn = n0 + colb + ni * 16 + lr;
#pragma unroll
      for (int j = 0; j < 4; ++j) C[(r0 + j) * N + cn] = acc[mi][ni][j];
    }
}

// ---------------------------------------------------------------- flash attention
// R14 structure (156us: 8 waves, KVBLK=128, q=32/wave, zero-conflict XOR LDS,
// in-register P, O^T accumulate, defer-max, setprio, XCD swizzle) restructured
// into a ONE-ITER SKEW: body u computes PV(u) INTERLEAVED with QK(u+1), then
// SM(u+1) at body end (off the MFMA critical path; overlaps other wave's MFMA).
// Buffer timing: K(u+2) issued in body u -> kbuf[u&1] (QK(u) done in body u-1);
// V(u+1) issued in body u -> vbuf[(u+1)&1] (PV(u) reads vbuf[u&1]). Dbuf holds.
__global__ void __launch_bounds__(512)
attn_kernel(const u16* __restrict__ qg, const u16* __restrict__ kg,
            const u16* __restrict__ vtg, u16* __restrict__ og) {
  __shared__ alignas(64) char smb[131072];
  const int tid = threadIdx.x;
  const int w = tid >> 6, lane = tid & 63;
  const int ql = lane & 31, hl = lane >> 5;
  const int gb = (blockIdx.x & 7) * 32 + (blockIdx.x >> 3);  // XCD swizzle (256=8*32)
  const int h = gb >> 4;
  const int qb = gb & 15;

  // staging: waves 0-3 -> K tile [128][256B], waves 4-7 -> V tile [128 d][256B]
  // Both: LDS slot m of row r holds source 16B-block m^(r&15).
  const u16* ssrc[8];
  unsigned sdst[8];
  size_t sstep;
  if (w < 4) {
    sstep = 128 * 128;
#pragma unroll
    for (int i = 0; i < 8; ++i) {
      int c = w * 8 + i;
      int r = c * 4 + (lane >> 4);
      int sb = (lane & 15) ^ (r & 15);
      ssrc[i] = kg + (size_t)(h * 4096 + r) * 128 + sb * 8;
      sdst[i] = c * 1024;
    }
  } else {
    sstep = 128;
#pragma unroll
    for (int i = 0; i < 8; ++i) {
      int c = (w - 4) * 8 + i;
      int r = c * 4 + (lane >> 4);
      int sb = (lane & 15) ^ (r & 15);
      ssrc[i] = vtg + (size_t)(h * 128 + r) * 4096 + sb * 8;
      sdst[i] = 65536 + c * 1024;
    }
  }

  // Q fragments (pre-scaled by scale*log2e at GEMM1 epilogue)
  const u16* qrow = qg + (size_t)(h * 4096 + qb * 256 + w * 32 + ql) * 128 + hl * 8;
  bf16x8 qf[8];
#pragma unroll
  for (int s = 0; s < 8; ++s) qf[s] = *(const bf16x8*)(qrow + s * 16);

  f32x16 of[4];
#pragma unroll
  for (int i = 0; i < 4; ++i)
#pragma unroll
    for (int r = 0; r < 16; ++r) of[i][r] = 0.f;
  float mrun = -1e30f, lsum = 0.f;
  const float thr = 6.0f;
  const int kxor = (ql & 15) << 4;

  union U { unsigned u[4]; bf16x8 v; };
  U paf[8];
  float escc = 1.f;
  bool rflag = false;

  // SM: consume st (QK(t) output) -> paf(t), update mrun/lsum, set rflag/escc
  f32x16 st[4];
  auto SM = [&]() {
    float tmax = -1e30f;
#pragma unroll
    for (int kb = 0; kb < 4; ++kb)
#pragma unroll
      for (int r = 0; r < 16; ++r) tmax = fmaxf(tmax, st[kb][r]);
    tmax = fmaxf(tmax, __shfl_xor(tmax, 32));
    if (!__all(tmax - mrun <= thr)) {
      float mnew = fmaxf(mrun, tmax);
      escc = EXP2(mrun - mnew);
      lsum *= escc;
      mrun = mnew;
      rflag = true;
    } else {
      rflag = false;
    }
    float psum = 0.f;
#pragma unroll
    for (int gp = 0; gp < 2; ++gp) {
      unsigned pk0[8], pk1[8];
#pragma unroll
      for (int i = 0; i < 8; ++i) {
        float a0 = EXP2(st[2 * gp + 0][2 * i] - mrun);
        float b0 = EXP2(st[2 * gp + 0][2 * i + 1] - mrun);
        float a1 = EXP2(st[2 * gp + 1][2 * i] - mrun);
        float b1 = EXP2(st[2 * gp + 1][2 * i + 1] - mrun);
        psum += (a0 + b0) + (a1 + b1);
        pk0[i] = cvtpk(a0, b0);
        pk1[i] = cvtpk(a1, b1);
      }
      pl32swap(pk0[0], pk0[2]); pl32swap(pk0[1], pk0[3]);
      pl32swap(pk0[4], pk0[6]); pl32swap(pk0[5], pk0[7]);
      pl32swap(pk1[0], pk1[2]); pl32swap(pk1[1], pk1[3]);
      pl32swap(pk1[4], pk1[6]); pl32swap(pk1[5], pk1[7]);
#pragma unroll
      for (int i = 0; i < 4; ++i) {
        paf[gp * 4 + 0].u[i] = pk0[i];
        paf[gp * 4 + 1].u[i] = pk0[4 + i];
        paf[gp * 4 + 2].u[i] = pk1[i];
        paf[gp * 4 + 3].u[i] = pk1[4 + i];
      }
    }
    psum += __shfl_xor(psum, 32);
    lsum += psum;
  };

  auto QKs = [&](const char* kbuf, int s) {  // one QK step: 4 reads + 4 MFMA
    int off = ((s * 2 + hl) << 4) ^ kxor;
    bf16x8 k0 = *(const bf16x8*)(kbuf + (0 * 32 + ql) * 256 + off);
    bf16x8 k1 = *(const bf16x8*)(kbuf + (1 * 32 + ql) * 256 + off);
    bf16x8 k2 = *(const bf16x8*)(kbuf + (2 * 32 + ql) * 256 + off);
    bf16x8 k3 = *(const bf16x8*)(kbuf + (3 * 32 + ql) * 256 + off);
    st[0] = MFMA32(k0, qf[s], st[0]);
    st[1] = MFMA32(k1, qf[s], st[1]);
    st[2] = MFMA32(k2, qf[s], st[2]);
    st[3] = MFMA32(k3, qf[s], st[3]);
  };
  auto PVdb = [&](const char* vbuf, int db) {  // one PV block: 8 reads + 8 MFMA
    const char* vrow = vbuf + (db * 32 + ql) * 256;
#pragma unroll
    for (int kp = 0; kp < 8; ++kp) {
      int m = (kp * 2 + hl) ^ (ql & 15);
      bf16x8 vf = *(const bf16x8*)(vrow + m * 16);
      of[db] = MFMA32(vf, paf[kp].v, of[db]);
    }
  };

  // ---- prologue: K(0),V(0); barrier; issue K(1); QK(0); SM(0)
#pragma unroll
  for (int i = 0; i < 8; ++i) gload16(ssrc[i], smb + sdst[i]);
  asm volatile("s_waitcnt vmcnt(0)" ::: "memory");
  BARRIER;
  if (w < 4) {
#pragma unroll
    for (int i = 0; i < 8; ++i)
      gload16(ssrc[i] + sstep, smb + sdst[i] + 32768);
  }
#pragma unroll
  for (int kb = 0; kb < 4; ++kb)
#pragma unroll
    for (int r = 0; r < 16; ++r) st[kb][r] = 0.f;
  __builtin_amdgcn_s_setprio(1);
#pragma unroll
  for (int s = 0; s < 8; ++s) QKs(smb, s);
  __builtin_amdgcn_s_setprio(0);
  SM();

  // ---- skewed main loop
  for (int u = 0; u < 32; ++u) {
    asm volatile("s_waitcnt vmcnt(0)" ::: "memory");
    __builtin_amdgcn_s_barrier();
    FENCE;
    if (w < 4) {
      if (u < 30) {
        const int nb = u & 1;
#pragma unroll
        for (int i = 0; i < 8; ++i)
          gload16(ssrc[i] + (size_t)(u + 2) * sstep, smb + sdst[i] + nb * 32768);
      }
    } else {
      if (u < 31) {
        const int nb = (u + 1) & 1;
#pragma unroll
        for (int i = 0; i < 8; ++i)
          gload16(ssrc[i] + (size_t)(u + 1) * sstep, smb + sdst[i] + nb * 32768);
      }
    }
    const char* kbuf = smb + ((u + 1) & 1) * 32768;          // K(u+1)
    const char* vbuf = smb + 65536 + (u & 1) * 32768;        // V(u)

    if (rflag) {
#pragma unroll
      for (int db = 0; db < 4; ++db)
#pragma unroll
        for (int r = 0; r < 16; ++r) of[db][r] *= escc;
    }

    if (u < 31) {
      // QK(u+1) interleaved with PV(u): independent MFMA streams
#pragma unroll
      for (int kb = 0; kb < 4; ++kb)
#pragma unroll
        for (int r = 0; r < 16; ++r) st[kb][r] = 0.f;
      __builtin_amdgcn_s_setprio(1);
#pragma unroll
      for (int s = 0; s < 4; ++s) {
        QKs(kbuf, s);
        PVdb(vbuf, s);
      }
#pragma unroll
      for (int s = 4; s < 8; ++s) QKs(kbuf, s);
      __builtin_amdgcn_s_setprio(0);
      SM();  // SM(u+1): off the MFMA critical path
    } else {
      __builtin_amdgcn_s_setprio(1);
#pragma unroll
      for (int db = 0; db < 4; ++db) PVdb(vbuf, db);
      __builtin_amdgcn_s_setprio(0);
    }
    FENCE;
  }

  // epilogue: lane owns q = ql; d = db*32 + (r&3) + 8*(r>>2) + 4*hl
  float linv = 1.f / (lsum + 1e-8f);
  size_t qrow_o = (size_t)(qb * 256 + w * 32 + ql) * 2048 + h * 128;
#pragma unroll
  for (int db = 0; db < 4; ++db)
#pragma unroll
    for (int u = 0; u < 4; ++u) {
      ushort4 pk;
      pk.x = f2bf(of[db][4 * u + 0] * linv);
      pk.y = f2bf(of[db][4 * u + 1] * linv);
      pk.z = f2bf(of[db][4 * u + 2] * linv);
      pk.w = f2bf(of[db][4 * u + 3] * linv);
      *(ushort4*)(og + qrow_o + db * 32 + 8 * u + hl * 4) = pk;
    }
}

// ---------------------------------------------------------------- launcher
extern "C" void kernel_launch(void* const* d_in, const int* in_sizes, int n_in,
                              void* d_out, int out_size, void* d_ws, size_t ws_size,
                              hipStream_t stream) {
  const float* x = (const float*)d_in[0];      // [4096][2048]
  const float* w_qkv = (const float*)d_in[1];  // [6144][2048]
  const float* w_out = (const float*)d_in[2];  // [2048][2048]

  char* ws = (char*)d_ws;
  u16* xb = (u16*)(ws + 0);            // 16 MB
  u16* wqkvb = (u16*)(ws + 16777216);  // 24 MB
  u16* woutb = (u16*)(ws + 41943040);  // 8 MB
  u16* qb = (u16*)(ws + 50331648);     // 16 MB  [NH][S][HD] (pre-scaled)
  u16* kb = (u16*)(ws + 67108864);     // 16 MB  [NH][S][HD]
  u16* vtb = (u16*)(ws + 83886080);    // 16 MB  [NH][HD][S]
  u16* aob = (u16*)(ws + 100663296);   // 16 MB  [S][H]

  cast_bf16<<<8192, 256, 0, stream>>>(x, xb, 2097152);
  cast_bf16<<<12288, 256, 0, stream>>>(w_qkv, wqkvb, 3145728);
  cast_bf16<<<4096, 256, 0, stream>>>(w_out, woutb, 1048576);

  gemm8<0><<<384, 512, 0, stream>>>(xb, wqkvb, qb, kb, vtb, 4096, 6144, 2048, 16);
  attn_kernel<<<256, 512, 0, stream>>>(qb, kb, vtb, aob);
  gemm_bt<1><<<512, 256, 0, stream>>>(aob, woutb, d_out, nullptr, nullptr, 4096, 2048, 2048, 32);
}

// Round 17
// 314.502 us; speedup vs baseline: 1.1513x; 1.0505x over previous
//
#include <hip/hip_runtime.h>
#include <stdint.h>

typedef __attribute__((ext_vector_type(4))) float f32x4;
typedef __attribute__((ext_vector_type(16))) float f32x16;
typedef __attribute__((ext_vector_type(8))) short bf16x8;
typedef unsigned short u16;

#define MFMA(a, b, c) __builtin_amdgcn_mfma_f32_16x16x32_bf16(a, b, c, 0, 0, 0)
#define MFMA32(a, b, c) __builtin_amdgcn_mfma_f32_32x32x16_bf16(a, b, c, 0, 0, 0)
#define EXP2(x) __builtin_amdgcn_exp2f(x)
#define FENCE asm volatile("" ::: "memory")
#define BARRIER do { FENCE; __builtin_amdgcn_s_barrier(); FENCE; } while (0)

__device__ __forceinline__ u16 f2bf(float f) {
  union { float f; unsigned u; } x; x.f = f;
  unsigned r = x.u + 0x7fffu + ((x.u >> 16) & 1u);
  return (u16)(r >> 16);
}

__device__ __forceinline__ unsigned cvtpk(float lo, float hi) {
  unsigned r;
  asm("v_cvt_pk_bf16_f32 %0, %1, %2" : "=v"(r) : "v"(lo), "v"(hi));
  return r;
}

__device__ __forceinline__ void pl32swap(unsigned& a, unsigned& b) {
  asm volatile("v_permlane32_swap_b32 %0, %1" : "+v"(a), "+v"(b));
}

__device__ __forceinline__ void gload16(const void* g, void* l) {
  __builtin_amdgcn_global_load_lds(
      (const __attribute__((address_space(1))) unsigned int*)g,
      (__attribute__((address_space(3))) unsigned int*)l, 16, 0, 0);
}

// ---------------------------------------------------------------- cast f32->bf16
__global__ void __launch_bounds__(256) cast_bf16(const float* __restrict__ in,
                                                 u16* __restrict__ out, int n4) {
  int i = blockIdx.x * 256 + threadIdx.x;
  if (i >= n4) return;
  float4 v = reinterpret_cast<const float4*>(in)[i];
  ushort4 o;
  o.x = f2bf(v.x); o.y = f2bf(v.y); o.z = f2bf(v.z); o.w = f2bf(v.w);
  reinterpret_cast<ushort4*>(out)[i] = o;
}

// ---------------------------------------------------------------- 8-phase GEMM, BM=128 x BN=256
// C = A * B^T. Exact-fill grids: GEMM1 32x24=768 blocks (3 rounds), GEMM2 32x8=256 (1 round).
// 8 waves (2M x 4N), wave tile 64x64, acc[4][4], BK=64.
// LDS 96KB: A dbuf 2x16KB @0, B dbuf 2x32KB @32768. Slot-XOR (r&7) layout, proven zero-conflict.
// Stage units/tile: u0=A-a(rows{0-31,64-95},1 gload/wave), u1=B-1(rows{0-31,64-95,128-159,192-223},2),
// u2=A-b(+32,1), u3=B-2(+32,2) -> 6 gloads/wave/tile; counted vmcnt(4) at ph4/ph8
// (drain leaves exactly next tile's u0,u1,u2 = 4 in flight). Region safety: each unit
// staged >=1 barrier after its last read (A-a read ph1/staged ph2; B-1 ph1/ph3; A-b ph3/ph4; B-2 ph2/ph5).
template <int EPI>
__global__ void __launch_bounds__(512)
gemm8(const u16* __restrict__ A, const u16* __restrict__ B,
      void* __restrict__ C0, void* __restrict__ C1, void* __restrict__ C2,
      int M, int N, int K, int MBt) {
  __shared__ alignas(16) char smb[98304];
  const int tid = threadIdx.x;
  const int w = tid >> 6, lane = tid & 63;
  const int lr = lane & 15, g = lane >> 4;
  const int wm = w >> 2, wn = w & 3;
  const int gb = (blockIdx.x & 7) * ((int)gridDim.x >> 3) + (blockIdx.x >> 3);
  const int mb = gb % MBt, nb = gb / MBt;
  const int m0 = mb * 128, n0 = nb * 256;
  const int NT = K >> 6, NIT = NT >> 1;

  const int l8 = lane >> 3, l7 = lane & 7;
  const int csb = (l7 ^ l8) * 16;  // pre-swizzled source byte col
  // A: 8 chunks of 1KB, chunk = w (1 gload/wave)
  const char* asrc;
  unsigned adst;
  {
    int r = (w & 3) * 8 + ((w >> 2) << 6) + l8;  // A-a rows {0-31, 64-95}
    asrc = (const char*)(A + (size_t)(m0 + r) * K) + csb;
    adst = (unsigned)(r * 128 + l7 * 16);
  }
  // B: 16 chunks, chunks 2w,2w+1 (2 gloads/wave)
  const char* bsrcb[2];
  unsigned bdst[2];
#pragma unroll
  for (int j = 0; j < 2; ++j) {
    int c = 2 * w + j;
    int r = (c & 3) * 8 + ((c >> 2) << 6) + l8;  // B-1 rows {0-31,64-95,128-159,192-223}
    bsrcb[j] = (const char*)(B + (size_t)(n0 + r) * K) + csb;
    bdst[j] = (unsigned)(r * 128 + l7 * 16);
  }
  const size_t row32 = (size_t)32 * K * 2;  // +32-row source offset (A-b / B-2)

#define STG(kt, u)                                                               \
  do {                                                                           \
    if ((kt) < NT) {                                                             \
      size_t _ko = (size_t)(kt) * 128;                                           \
      int _da = ((kt) & 1) ? 16384 : 0;                                          \
      int _db = 32768 + (((kt) & 1) ? 32768 : 0);                                \
      if ((u) == 0) {                                                            \
        gload16(asrc + _ko, smb + _da + adst);                                   \
      } else if ((u) == 1) {                                                     \
        gload16(bsrcb[0] + _ko, smb + _db + bdst[0]);                            \
        gload16(bsrcb[1] + _ko, smb + _db + bdst[1]);                            \
      } else if ((u) == 2) {                                                     \
        gload16(asrc + row32 + _ko, smb + _da + 4096 + adst);                    \
      } else {                                                                   \
        gload16(bsrcb[0] + row32 + _ko, smb + _db + 4096 + bdst[0]);             \
        gload16(bsrcb[1] + row32 + _ko, smb + _db + 4096 + bdst[1]);             \
      }                                                                          \
    }                                                                            \
  } while (0)

  f32x4 acc[4][4];
#pragma unroll
  for (int x = 0; x < 4; ++x)
#pragma unroll
    for (int y = 0; y < 4; ++y) acc[x][y] = f32x4{0.f, 0.f, 0.f, 0.f};
  bf16x8 af[2][2], bf01[2][2], bf23[2][2];
  const int aoff0 = ((g) ^ (lr & 7)) << 4;      // ks=0 slot
  const int aoff1 = ((4 + g) ^ (lr & 7)) << 4;  // ks=1 slot
  const int arowb = (wm * 64 + lr) * 128;
  const int browb = (wn * 64 + lr) * 128;

  auto LDA = [&](const char* base, int mih) {
#pragma unroll
    for (int mi = 0; mi < 2; ++mi) {
      const char* p = base + arowb + (mih * 32 + mi * 16) * 128;
      af[mi][0] = *(const bf16x8*)(p + aoff0);
      af[mi][1] = *(const bf16x8*)(p + aoff1);
    }
  };
  auto LDB = [&](const char* base, bf16x8 (*bfr)[2], int nih) {
#pragma unroll
    for (int ni = 0; ni < 2; ++ni) {
      const char* p = base + browb + (nih * 32 + ni * 16) * 128;
      bfr[ni][0] = *(const bf16x8*)(p + aoff0);
      bfr[ni][1] = *(const bf16x8*)(p + aoff1);
    }
  };
  auto MM = [&](int mih, int nih, bf16x8 (*bfr)[2]) {
    __builtin_amdgcn_s_setprio(1);
#pragma unroll
    for (int mi = 0; mi < 2; ++mi)
#pragma unroll
      for (int ni = 0; ni < 2; ++ni) {
        acc[mih * 2 + mi][nih * 2 + ni] =
            MFMA(af[mi][0], bfr[ni][0], acc[mih * 2 + mi][nih * 2 + ni]);
        acc[mih * 2 + mi][nih * 2 + ni] =
            MFMA(af[mi][1], bfr[ni][1], acc[mih * 2 + mi][nih * 2 + ni]);
      }
    __builtin_amdgcn_s_setprio(0);
  };

  // prologue: tile0 fully + tile1 {A-a,B-1,A-b}; wait for tile0 (oldest 6 of 10)
  STG(0, 0); STG(0, 1); STG(0, 2); STG(0, 3);
  STG(1, 0); STG(1, 1); STG(1, 2);
  asm volatile("s_waitcnt vmcnt(4)" ::: "memory");
  BARRIER;

  const char* A0 = smb;
  const char* A1 = smb + 16384;
  const char* B0 = smb + 32768;
  const char* B1 = smb + 65536;

  for (int it = 0; it < NIT; ++it) {
    const int t0 = 2 * it;
    const bool lastit = (it == NIT - 1);
    LDA(A0, 0); LDB(B0, bf01, 0); STG(t0 + 1, 3);
    BARRIER; MM(0, 0, bf01); BARRIER;
    LDB(B0, bf23, 1); STG(t0 + 2, 0);
    BARRIER; MM(0, 1, bf23); BARRIER;
    LDA(A0, 1); STG(t0 + 2, 1);
    BARRIER; MM(1, 1, bf23); BARRIER;
    STG(t0 + 2, 2);
    if (lastit) asm volatile("s_waitcnt vmcnt(0)" ::: "memory");
    else        asm volatile("s_waitcnt vmcnt(4)" ::: "memory");
    BARRIER; MM(1, 0, bf01); BARRIER;
    LDA(A1, 0); LDB(B1, bf01, 0); STG(t0 + 2, 3);
    BARRIER; MM(0, 0, bf01); BARRIER;
    LDB(B1, bf23, 1); STG(t0 + 3, 0);
    BARRIER; MM(0, 1, bf23); BARRIER;
    LDA(A1, 1); STG(t0 + 3, 1);
    BARRIER; MM(1, 1, bf23); BARRIER;
    STG(t0 + 3, 2);
    asm volatile("s_waitcnt vmcnt(4)" ::: "memory");
    BARRIER; MM(1, 0, bf01); BARRIER;
  }
#undef STG

  // epilogue: C/D layout col = lr, row = g*4 + j
  if (EPI == 0) {
    const float qs = 0.08838834764831845f * 1.4426950408889634f;  // scale*log2e
    u16* qo = (u16*)C0;
    u16* ko = (u16*)C1;
    u16* vo = (u16*)C2;
#pragma unroll
    for (int a = 0; a < 4; ++a) {
      int s0 = m0 + wm * 64 + a * 16 + g * 4;
#pragma unroll
      for (int b = 0; b < 4; ++b) {
        int n = n0 + wn * 64 + b * 16 + lr;
        int t = n >> 11, hh = (n >> 7) & 15, d = n & 127;
        if (t == 2) {  // v transposed: [NH][HD][S]
          ushort4 pk;
          pk.x = f2bf(acc[a][b][0]);
          pk.y = f2bf(acc[a][b][1]);
          pk.z = f2bf(acc[a][b][2]);
          pk.w = f2bf(acc[a][b][3]);
          *(ushort4*)(vo + (size_t)(hh * 128 + d) * 4096 + s0) = pk;
        } else {
          float sc = (t == 0) ? qs : 1.f;
          u16* dq = (t == 0 ? qo : ko) + (size_t)(hh * 4096 + s0) * 128 + d;
#pragma unroll
          for (int j = 0; j < 4; ++j) dq[(size_t)j * 128] = f2bf(acc[a][b][j] * sc);
        }
      }
    }
  } else {
    float* C = (float*)C0;
#pragma unroll
    for (int a = 0; a < 4; ++a)
#pragma unroll
      for (int b = 0; b < 4; ++b) {
        size_t r0 = (size_t)(m0 + wm * 64 + a * 16 + g * 4);
        int cn = n0 + wn * 64 + b * 16 + lr;
#pragma unroll
        for (int j = 0; j < 4; ++j) C[(r0 + j) * N + cn] = acc[a][b][j];
      }
  }
}

// ---------------------------------------------------------------- flash attention (R14, 156us proven)
// 8 waves / 512 thr, grid 256 = 1 block/CU, q=32/wave, KVBLK=128 (32 iters),
// zero-conflict 4-bit-XOR LDS for K and V, in-register P (cvt_pk+permlane32_swap),
// O^T accumulate, defer-max, setprio, XCD swizzle.
__global__ void __launch_bounds__(512)
attn_kernel(const u16* __restrict__ qg, const u16* __restrict__ kg,
            const u16* __restrict__ vtg, u16* __restrict__ og) {
  __shared__ alignas(64) char smb[131072];
  const int tid = threadIdx.x;
  const int w = tid >> 6, lane = tid & 63;
  const int ql = lane & 31, hl = lane >> 5;
  const int gb = (blockIdx.x & 7) * 32 + (blockIdx.x >> 3);  // XCD swizzle (256=8*32)
  const int h = gb >> 4;
  const int qb = gb & 15;

  const u16* ssrc[8];
  unsigned sdst[8];
  size_t sstep;
  if (w < 4) {
    sstep = 128 * 128;
#pragma unroll
    for (int i = 0; i < 8; ++i) {
      int c = w * 8 + i;
      int r = c * 4 + (lane >> 4);
      int sb = (lane & 15) ^ (r & 15);
      ssrc[i] = kg + (size_t)(h * 4096 + r) * 128 + sb * 8;
      sdst[i] = c * 1024;
    }
  } else {
    sstep = 128;
#pragma unroll
    for (int i = 0; i < 8; ++i) {
      int c = (w - 4) * 8 + i;
      int r = c * 4 + (lane >> 4);
      int sb = (lane & 15) ^ (r & 15);
      ssrc[i] = vtg + (size_t)(h * 128 + r) * 4096 + sb * 8;
      sdst[i] = 65536 + c * 1024;
    }
  }

  const u16* qrow = qg + (size_t)(h * 4096 + qb * 256 + w * 32 + ql) * 128 + hl * 8;
  bf16x8 qf[8];
#pragma unroll
  for (int s = 0; s < 8; ++s) qf[s] = *(const bf16x8*)(qrow + s * 16);

  f32x16 of[4];
#pragma unroll
  for (int i = 0; i < 4; ++i)
#pragma unroll
    for (int r = 0; r < 16; ++r) of[i][r] = 0.f;
  float mrun = -1e30f, lsum = 0.f;
  const float thr = 6.0f;

#pragma unroll
  for (int i = 0; i < 8; ++i) gload16(ssrc[i], smb + sdst[i]);

  const int kxor = (ql & 15) << 4;
  for (int t = 0; t < 32; ++t) {
    const int cur = t & 1;
    asm volatile("s_waitcnt vmcnt(0)" ::: "memory");
    __builtin_amdgcn_s_barrier();
    FENCE;
    if (t + 1 < 32) {
      const int nb = (t + 1) & 1;
#pragma unroll
      for (int i = 0; i < 8; ++i)
        gload16(ssrc[i] + (size_t)(t + 1) * sstep, smb + sdst[i] + nb * 32768);
    }
    const char* kbuf = smb + cur * 32768;
    const char* vbuf = smb + 65536 + cur * 32768;

    f32x16 st[4];
#pragma unroll
    for (int kb = 0; kb < 4; ++kb)
#pragma unroll
      for (int r = 0; r < 16; ++r) st[kb][r] = 0.f;
    __builtin_amdgcn_s_setprio(1);
#pragma unroll
    for (int s = 0; s < 8; ++s) {
      int off = ((s * 2 + hl) << 4) ^ kxor;
      bf16x8 k0 = *(const bf16x8*)(kbuf + (0 * 32 + ql) * 256 + off);
      bf16x8 k1 = *(const bf16x8*)(kbuf + (1 * 32 + ql) * 256 + off);
      bf16x8 k2 = *(const bf16x8*)(kbuf + (2 * 32 + ql) * 256 + off);
      bf16x8 k3 = *(const bf16x8*)(kbuf + (3 * 32 + ql) * 256 + off);
      st[0] = MFMA32(k0, qf[s], st[0]);
      st[1] = MFMA32(k1, qf[s], st[1]);
      st[2] = MFMA32(k2, qf[s], st[2]);
      st[3] = MFMA32(k3, qf[s], st[3]);
    }
    __builtin_amdgcn_s_setprio(0);

    float tmax = -1e30f;
#pragma unroll
    for (int kb = 0; kb < 4; ++kb)
#pragma unroll
      for (int r = 0; r < 16; ++r) tmax = fmaxf(tmax, st[kb][r]);
    tmax = fmaxf(tmax, __shfl_xor(tmax, 32));
    if (!__all(tmax - mrun <= thr)) {
      float mnew = fmaxf(mrun, tmax);
      float esc = EXP2(mrun - mnew);
#pragma unroll
      for (int db = 0; db < 4; ++db)
#pragma unroll
        for (int r = 0; r < 16; ++r) of[db][r] *= esc;
      lsum *= esc;
      mrun = mnew;
    }
    float psum = 0.f;
    union U { unsigned u[4]; bf16x8 v; };
    U paf[8];
#pragma unroll
    for (int gp = 0; gp < 2; ++gp) {
      unsigned pk0[8], pk1[8];
#pragma unroll
      for (int i = 0; i < 8; ++i) {
        float a0 = EXP2(st[2 * gp + 0][2 * i] - mrun);
        float b0 = EXP2(st[2 * gp + 0][2 * i + 1] - mrun);
        float a1 = EXP2(st[2 * gp + 1][2 * i] - mrun);
        float b1 = EXP2(st[2 * gp + 1][2 * i + 1] - mrun);
        psum += (a0 + b0) + (a1 + b1);
        pk0[i] = cvtpk(a0, b0);
        pk1[i] = cvtpk(a1, b1);
      }
      pl32swap(pk0[0], pk0[2]); pl32swap(pk0[1], pk0[3]);
      pl32swap(pk0[4], pk0[6]); pl32swap(pk0[5], pk0[7]);
      pl32swap(pk1[0], pk1[2]); pl32swap(pk1[1], pk1[3]);
      pl32swap(pk1[4], pk1[6]); pl32swap(pk1[5], pk1[7]);
#pragma unroll
      for (int i = 0; i < 4; ++i) {
        paf[gp * 4 + 0].u[i] = pk0[i];
        paf[gp * 4 + 1].u[i] = pk0[4 + i];
        paf[gp * 4 + 2].u[i] = pk1[i];
        paf[gp * 4 + 3].u[i] = pk1[4 + i];
      }
    }
    psum += __shfl_xor(psum, 32);
    lsum += psum;

    __builtin_amdgcn_s_setprio(1);
#pragma unroll
    for (int db = 0; db < 4; ++db) {
      const char* vrow = vbuf + (db * 32 + ql) * 256;
#pragma unroll
      for (int kp = 0; kp < 8; ++kp) {
        int m = (kp * 2 + hl) ^ (ql & 15);
        bf16x8 vf = *(const bf16x8*)(vrow + m * 16);
        of[db] = MFMA32(vf, paf[kp].v, of[db]);
      }
    }
    __builtin_amdgcn_s_setprio(0);
    FENCE;
  }

  float linv = 1.f / (lsum + 1e-8f);
  size_t qrow_o = (size_t)(qb * 256 + w * 32 + ql) * 2048 + h * 128;
#pragma unroll
  for (int db = 0; db < 4; ++db)
#pragma unroll
    for (int u = 0; u < 4; ++u) {
      ushort4 pk;
      pk.x = f2bf(of[db][4 * u + 0] * linv);
      pk.y = f2bf(of[db][4 * u + 1] * linv);
      pk.z = f2bf(of[db][4 * u + 2] * linv);
      pk.w = f2bf(of[db][4 * u + 3] * linv);
      *(ushort4*)(og + qrow_o + db * 32 + 8 * u + hl * 4) = pk;
    }
}

// ---------------------------------------------------------------- launcher
extern "C" void kernel_launch(void* const* d_in, const int* in_sizes, int n_in,
                              void* d_out, int out_size, void* d_ws, size_t ws_size,
                              hipStream_t stream) {
  const float* x = (const float*)d_in[0];      // [4096][2048]
  const float* w_qkv = (const float*)d_in[1];  // [6144][2048]
  const float* w_out = (const float*)d_in[2];  // [2048][2048]

  char* ws = (char*)d_ws;
  u16* xb = (u16*)(ws + 0);            // 16 MB
  u16* wqkvb = (u16*)(ws + 16777216);  // 24 MB
  u16* woutb = (u16*)(ws + 41943040);  // 8 MB
  u16* qb = (u16*)(ws + 50331648);     // 16 MB  [NH][S][HD] (pre-scaled)
  u16* kb = (u16*)(ws + 67108864);     // 16 MB  [NH][S][HD]
  u16* vtb = (u16*)(ws + 83886080);    // 16 MB  [NH][HD][S]
  u16* aob = (u16*)(ws + 100663296);   // 16 MB  [S][H]

  cast_bf16<<<8192, 256, 0, stream>>>(x, xb, 2097152);
  cast_bf16<<<12288, 256, 0, stream>>>(w_qkv, wqkvb, 3145728);
  cast_bf16<<<4096, 256, 0, stream>>>(w_out, woutb, 1048576);

  gemm8<0><<<768, 512, 0, stream>>>(xb, wqkvb, qb, kb, vtb, 4096, 6144, 2048, 32);
  attn_kernel<<<256, 512, 0, stream>>>(qb, kb, vtb, aob);
  gemm8<1><<<256, 512, 0, stream>>>(aob, woutb, d_out, nullptr, nullptr, 4096, 2048, 2048, 32);
}

// Round 18
// 312.316 us; speedup vs baseline: 1.1594x; 1.0070x over previous
//
#include <hip/hip_runtime.h>
#include <stdint.h>

typedef __attribute__((ext_vector_type(4))) float f32x4;
typedef __attribute__((ext_vector_type(16))) float f32x16;
typedef __attribute__((ext_vector_type(8))) short bf16x8;
typedef unsigned short u16;

#define MFMA(a, b, c) __builtin_amdgcn_mfma_f32_16x16x32_bf16(a, b, c, 0, 0, 0)
#define MFMA32(a, b, c) __builtin_amdgcn_mfma_f32_32x32x16_bf16(a, b, c, 0, 0, 0)
#define EXP2(x) __builtin_amdgcn_exp2f(x)
#define FENCE asm volatile("" ::: "memory")
#define BARRIER do { FENCE; __builtin_amdgcn_s_barrier(); FENCE; } while (0)

__device__ __forceinline__ u16 f2bf(float f) {
  union { float f; unsigned u; } x; x.f = f;
  unsigned r = x.u + 0x7fffu + ((x.u >> 16) & 1u);
  return (u16)(r >> 16);
}

__device__ __forceinline__ unsigned cvtpk(float lo, float hi) {
  unsigned r;
  asm("v_cvt_pk_bf16_f32 %0, %1, %2" : "=v"(r) : "v"(lo), "v"(hi));
  return r;
}

__device__ __forceinline__ void pl32swap(unsigned& a, unsigned& b) {
  asm volatile("v_permlane32_swap_b32 %0, %1" : "+v"(a), "+v"(b));
}

__device__ __forceinline__ void gload16(const void* g, void* l) {
  __builtin_amdgcn_global_load_lds(
      (const __attribute__((address_space(1))) unsigned int*)g,
      (__attribute__((address_space(3))) unsigned int*)l, 16, 0, 0);
}

// ---------------------------------------------------------------- fused f32->bf16 casts
__global__ void __launch_bounds__(256)
cast_all(const float* __restrict__ x, const float* __restrict__ wq,
         const float* __restrict__ wo, u16* __restrict__ xb,
         u16* __restrict__ wqb, u16* __restrict__ wob) {
  for (int idx = blockIdx.x * 256 + threadIdx.x; idx < 6291456; idx += 256 * 2048) {
    const float* in;
    u16* out;
    int j;
    if (idx < 2097152) { in = x; out = xb; j = idx; }
    else if (idx < 5242880) { in = wq; out = wqb; j = idx - 2097152; }
    else { in = wo; out = wob; j = idx - 5242880; }
    float4 v = reinterpret_cast<const float4*>(in)[j];
    ushort4 o;
    o.x = f2bf(v.x); o.y = f2bf(v.y); o.z = f2bf(v.z); o.w = f2bf(v.w);
    reinterpret_cast<ushort4*>(out)[j] = o;
  }
}

// ---------------------------------------------------------------- 4-phase GEMM, BM=128 x BN=256
// C = A * B^T. Exact-fill grids: GEMM1 768 blocks (3 rounds), GEMM2 256 (1 round).
// 8 waves (2M x 4N), wave tile 64x64, acc[4][4], BK=64, 16 MFMA per barrier-cluster.
// LDS 96KB: A dbuf 2x16KB @0, B dbuf 2x32KB @32768; slot-XOR (r&7), zero-conflict.
// Units/tile (6 gloads/wave): u0=A-a[1], u1=B-1[2], u2=A-b[1], u3=B-2[2].
// Phases per iter (tiles t0,t0+1): phA0{rd Aa/B1/B2(t0); stg (t0+1,Ab); vmcnt(6)},
// phB0{rd Ab(t0); stg (t0+2,{Aa,B1,B2}); vmcnt(6)}, phA1{rd t0+1; stg (t0+2,Ab);
// vmcnt(6)}, phB1{rd Ab(t0+1); stg (t0+3,{Aa,B1,B2}); vmcnt(6)}. Ledger verified
// from prologue (11 issued, vmcnt(5)) through steady state; lastit overrides
// vmcnt(1)/(0) where the steady count would under-wait. Every region staged
// >=1 barrier after its last LDS read.
template <int EPI>
__global__ void __launch_bounds__(512)
gemm8(const u16* __restrict__ A, const u16* __restrict__ B,
      void* __restrict__ C0, void* __restrict__ C1, void* __restrict__ C2,
      int M, int N, int K, int MBt) {
  __shared__ alignas(16) char smb[98304];
  const int tid = threadIdx.x;
  const int w = tid >> 6, lane = tid & 63;
  const int lr = lane & 15, g = lane >> 4;
  const int wm = w >> 2, wn = w & 3;
  const int gb = (blockIdx.x & 7) * ((int)gridDim.x >> 3) + (blockIdx.x >> 3);
  const int mb = gb % MBt, nb = gb / MBt;
  const int m0 = mb * 128, n0 = nb * 256;
  const int NT = K >> 6, NIT = NT >> 1;

  const int l8 = lane >> 3, l7 = lane & 7;
  const int csb = (l7 ^ l8) * 16;
  const char* asrc;
  unsigned adst;
  {
    int r = (w & 3) * 8 + ((w >> 2) << 6) + l8;
    asrc = (const char*)(A + (size_t)(m0 + r) * K) + csb;
    adst = (unsigned)(r * 128 + l7 * 16);
  }
  const char* bsrcb[2];
  unsigned bdst[2];
#pragma unroll
  for (int j = 0; j < 2; ++j) {
    int c = 2 * w + j;
    int r = (c & 3) * 8 + ((c >> 2) << 6) + l8;
    bsrcb[j] = (const char*)(B + (size_t)(n0 + r) * K) + csb;
    bdst[j] = (unsigned)(r * 128 + l7 * 16);
  }
  const size_t row32 = (size_t)32 * K * 2;

#define STG(kt, u)                                                               \
  do {                                                                           \
    if ((kt) < NT) {                                                             \
      size_t _ko = (size_t)(kt) * 128;                                           \
      int _da = ((kt) & 1) ? 16384 : 0;                                          \
      int _db = 32768 + (((kt) & 1) ? 32768 : 0);                                \
      if ((u) == 0) {                                                            \
        gload16(asrc + _ko, smb + _da + adst);                                   \
      } else if ((u) == 1) {                                                     \
        gload16(bsrcb[0] + _ko, smb + _db + bdst[0]);                            \
        gload16(bsrcb[1] + _ko, smb + _db + bdst[1]);                            \
      } else if ((u) == 2) {                                                     \
        gload16(asrc + row32 + _ko, smb + _da + 4096 + adst);                    \
      } else {                                                                   \
        gload16(bsrcb[0] + row32 + _ko, smb + _db + 4096 + bdst[0]);             \
        gload16(bsrcb[1] + row32 + _ko, smb + _db + 4096 + bdst[1]);             \
      }                                                                          \
    }                                                                            \
  } while (0)
#define VMC(n) asm volatile("s_waitcnt vmcnt(" #n ")" ::: "memory")

  f32x4 acc[4][4];
#pragma unroll
  for (int x = 0; x < 4; ++x)
#pragma unroll
    for (int y = 0; y < 4; ++y) acc[x][y] = f32x4{0.f, 0.f, 0.f, 0.f};
  bf16x8 af[2][2], bf01[2][2], bf23[2][2];
  const int aoff0 = ((g) ^ (lr & 7)) << 4;
  const int aoff1 = ((4 + g) ^ (lr & 7)) << 4;
  const int arowb = (wm * 64 + lr) * 128;
  const int browb = (wn * 64 + lr) * 128;

  auto LDA = [&](const char* base, int mih) {
#pragma unroll
    for (int mi = 0; mi < 2; ++mi) {
      const char* p = base + arowb + (mih * 32 + mi * 16) * 128;
      af[mi][0] = *(const bf16x8*)(p + aoff0);
      af[mi][1] = *(const bf16x8*)(p + aoff1);
    }
  };
  auto LDB = [&](const char* base, bf16x8 (*bfr)[2], int nih) {
#pragma unroll
    for (int ni = 0; ni < 2; ++ni) {
      const char* p = base + browb + (nih * 32 + ni * 16) * 128;
      bfr[ni][0] = *(const bf16x8*)(p + aoff0);
      bfr[ni][1] = *(const bf16x8*)(p + aoff1);
    }
  };
  auto MM = [&](int mih, int nih, bf16x8 (*bfr)[2]) {
#pragma unroll
    for (int mi = 0; mi < 2; ++mi)
#pragma unroll
      for (int ni = 0; ni < 2; ++ni) {
        acc[mih * 2 + mi][nih * 2 + ni] =
            MFMA(af[mi][0], bfr[ni][0], acc[mih * 2 + mi][nih * 2 + ni]);
        acc[mih * 2 + mi][nih * 2 + ni] =
            MFMA(af[mi][1], bfr[ni][1], acc[mih * 2 + mi][nih * 2 + ni]);
      }
  };

  // prologue: tile0 full + tile1 {Aa,B1,B2} = 11 gloads; wait tile0's 6
  STG(0, 0); STG(0, 1); STG(0, 2); STG(0, 3);
  STG(1, 0); STG(1, 1); STG(1, 3);
  VMC(5);
  BARRIER;

  const char* A0 = smb;
  const char* A1 = smb + 16384;
  const char* B0 = smb + 32768;
  const char* B1 = smb + 65536;

  for (int it = 0; it < NIT; ++it) {
    const int t0 = 2 * it;
    const bool last = (it == NIT - 1);
    // phA0: reads Aa(t0), B1(t0), B2(t0)
    LDA(A0, 0); LDB(B0, bf01, 0); LDB(B0, bf23, 1);
    STG(t0 + 1, 2);
    VMC(6);
    BARRIER;
    __builtin_amdgcn_s_setprio(1); MM(0, 0, bf01); MM(0, 1, bf23); __builtin_amdgcn_s_setprio(0);
    BARRIER;
    // phB0: reads Ab(t0)
    LDA(A0, 1);
    STG(t0 + 2, 0); STG(t0 + 2, 1); STG(t0 + 2, 3);
    if (last) VMC(1); else VMC(6);
    BARRIER;
    __builtin_amdgcn_s_setprio(1); MM(1, 1, bf23); MM(1, 0, bf01); __builtin_amdgcn_s_setprio(0);
    BARRIER;
    // phA1: reads Aa(t0+1), B1(t0+1), B2(t0+1)
    LDA(A1, 0); LDB(B1, bf01, 0); LDB(B1, bf23, 1);
    STG(t0 + 2, 2);
    if (last) VMC(0); else VMC(6);
    BARRIER;
    __builtin_amdgcn_s_setprio(1); MM(0, 0, bf01); MM(0, 1, bf23); __builtin_amdgcn_s_setprio(0);
    BARRIER;
    // phB1: reads Ab(t0+1)
    LDA(A1, 1);
    STG(t0 + 3, 0); STG(t0 + 3, 1); STG(t0 + 3, 3);
    if (last) VMC(0); else VMC(6);
    BARRIER;
    __builtin_amdgcn_s_setprio(1); MM(1, 1, bf23); MM(1, 0, bf01); __builtin_amdgcn_s_setprio(0);
    BARRIER;
  }
#undef STG
#undef VMC

  // epilogue: C/D layout col = lr, row = g*4 + j
  if (EPI == 0) {
    const float qs = 0.08838834764831845f * 1.4426950408889634f;  // scale*log2e
    u16* qo = (u16*)C0;
    u16* ko = (u16*)C1;
    u16* vo = (u16*)C2;
#pragma unroll
    for (int a = 0; a < 4; ++a) {
      int s0 = m0 + wm * 64 + a * 16 + g * 4;
#pragma unroll
      for (int b = 0; b < 4; ++b) {
        int n = n0 + wn * 64 + b * 16 + lr;
        int t = n >> 11, hh = (n >> 7) & 15, d = n & 127;
        if (t == 2) {  // v transposed: [NH][HD][S]
          ushort4 pk;
          pk.x = f2bf(acc[a][b][0]);
          pk.y = f2bf(acc[a][b][1]);
          pk.z = f2bf(acc[a][b][2]);
          pk.w = f2bf(acc[a][b][3]);
          *(ushort4*)(vo + (size_t)(hh * 128 + d) * 4096 + s0) = pk;
        } else {
          float sc = (t == 0) ? qs : 1.f;
          u16* dq = (t == 0 ? qo : ko) + (size_t)(hh * 4096 + s0) * 128 + d;
#pragma unroll
          for (int j = 0; j < 4; ++j) dq[(size_t)j * 128] = f2bf(acc[a][b][j] * sc);
        }
      }
    }
  } else {
    float* C = (float*)C0;
#pragma unroll
    for (int a = 0; a < 4; ++a)
#pragma unroll
      for (int b = 0; b < 4; ++b) {
        size_t r0 = (size_t)(m0 + wm * 64 + a * 16 + g * 4);
        int cn = n0 + wn * 64 + b * 16 + lr;
#pragma unroll
        for (int j = 0; j < 4; ++j) C[(r0 + j) * N + cn] = acc[a][b][j];
      }
  }
}

// ---------------------------------------------------------------- flash attention (R14, 156us proven)
__global__ void __launch_bounds__(512)
attn_kernel(const u16* __restrict__ qg, const u16* __restrict__ kg,
            const u16* __restrict__ vtg, u16* __restrict__ og) {
  __shared__ alignas(64) char smb[131072];
  const int tid = threadIdx.x;
  const int w = tid >> 6, lane = tid & 63;
  const int ql = lane & 31, hl = lane >> 5;
  const int gb = (blockIdx.x & 7) * 32 + (blockIdx.x >> 3);  // XCD swizzle (256=8*32)
  const int h = gb >> 4;
  const int qb = gb & 15;

  const u16* ssrc[8];
  unsigned sdst[8];
  size_t sstep;
  if (w < 4) {
    sstep = 128 * 128;
#pragma unroll
    for (int i = 0; i < 8; ++i) {
      int c = w * 8 + i;
      int r = c * 4 + (lane >> 4);
      int sb = (lane & 15) ^ (r & 15);
      ssrc[i] = kg + (size_t)(h * 4096 + r) * 128 + sb * 8;
      sdst[i] = c * 1024;
    }
  } else {
    sstep = 128;
#pragma unroll
    for (int i = 0; i < 8; ++i) {
      int c = (w - 4) * 8 + i;
      int r = c * 4 + (lane >> 4);
      int sb = (lane & 15) ^ (r & 15);
      ssrc[i] = vtg + (size_t)(h * 128 + r) * 4096 + sb * 8;
      sdst[i] = 65536 + c * 1024;
    }
  }

  const u16* qrow = qg + (size_t)(h * 4096 + qb * 256 + w * 32 + ql) * 128 + hl * 8;
  bf16x8 qf[8];
#pragma unroll
  for (int s = 0; s < 8; ++s) qf[s] = *(const bf16x8*)(qrow + s * 16);

  f32x16 of[4];
#pragma unroll
  for (int i = 0; i < 4; ++i)
#pragma unroll
    for (int r = 0; r < 16; ++r) of[i][r] = 0.f;
  float mrun = -1e30f, lsum = 0.f;
  const float thr = 6.0f;

#pragma unroll
  for (int i = 0; i < 8; ++i) gload16(ssrc[i], smb + sdst[i]);

  const int kxor = (ql & 15) << 4;
  for (int t = 0; t < 32; ++t) {
    const int cur = t & 1;
    asm volatile("s_waitcnt vmcnt(0)" ::: "memory");
    __builtin_amdgcn_s_barrier();
    FENCE;
    if (t + 1 < 32) {
      const int nb = (t + 1) & 1;
#pragma unroll
      for (int i = 0; i < 8; ++i)
        gload16(ssrc[i] + (size_t)(t + 1) * sstep, smb + sdst[i] + nb * 32768);
    }
    const char* kbuf = smb + cur * 32768;
    const char* vbuf = smb + 65536 + cur * 32768;

    f32x16 st[4];
#pragma unroll
    for (int kb = 0; kb < 4; ++kb)
#pragma unroll
      for (int r = 0; r < 16; ++r) st[kb][r] = 0.f;
    __builtin_amdgcn_s_setprio(1);
#pragma unroll
    for (int s = 0; s < 8; ++s) {
      int off = ((s * 2 + hl) << 4) ^ kxor;
      bf16x8 k0 = *(const bf16x8*)(kbuf + (0 * 32 + ql) * 256 + off);
      bf16x8 k1 = *(const bf16x8*)(kbuf + (1 * 32 + ql) * 256 + off);
      bf16x8 k2 = *(const bf16x8*)(kbuf + (2 * 32 + ql) * 256 + off);
      bf16x8 k3 = *(const bf16x8*)(kbuf + (3 * 32 + ql) * 256 + off);
      st[0] = MFMA32(k0, qf[s], st[0]);
      st[1] = MFMA32(k1, qf[s], st[1]);
      st[2] = MFMA32(k2, qf[s], st[2]);
      st[3] = MFMA32(k3, qf[s], st[3]);
    }
    __builtin_amdgcn_s_setprio(0);

    float tmax = -1e30f;
#pragma unroll
    for (int kb = 0; kb < 4; ++kb)
#pragma unroll
      for (int r = 0; r < 16; ++r) tmax = fmaxf(tmax, st[kb][r]);
    tmax = fmaxf(tmax, __shfl_xor(tmax, 32));
    if (!__all(tmax - mrun <= thr)) {
      float mnew = fmaxf(mrun, tmax);
      float esc = EXP2(mrun - mnew);
#pragma unroll
      for (int db = 0; db < 4; ++db)
#pragma unroll
        for (int r = 0; r < 16; ++r) of[db][r] *= esc;
      lsum *= esc;
      mrun = mnew;
    }
    float psum = 0.f;
    union U { unsigned u[4]; bf16x8 v; };
    U paf[8];
#pragma unroll
    for (int gp = 0; gp < 2; ++gp) {
      unsigned pk0[8], pk1[8];
#pragma unroll
      for (int i = 0; i < 8; ++i) {
        float a0 = EXP2(st[2 * gp + 0][2 * i] - mrun);
        float b0 = EXP2(st[2 * gp + 0][2 * i + 1] - mrun);
        float a1 = EXP2(st[2 * gp + 1][2 * i] - mrun);
        float b1 = EXP2(st[2 * gp + 1][2 * i + 1] - mrun);
        psum += (a0 + b0) + (a1 + b1);
        pk0[i] = cvtpk(a0, b0);
        pk1[i] = cvtpk(a1, b1);
      }
      pl32swap(pk0[0], pk0[2]); pl32swap(pk0[1], pk0[3]);
      pl32swap(pk0[4], pk0[6]); pl32swap(pk0[5], pk0[7]);
      pl32swap(pk1[0], pk1[2]); pl32swap(pk1[1], pk1[3]);
      pl32swap(pk1[4], pk1[6]); pl32swap(pk1[5], pk1[7]);
#pragma unroll
      for (int i = 0; i < 4; ++i) {
        paf[gp * 4 + 0].u[i] = pk0[i];
        paf[gp * 4 + 1].u[i] = pk0[4 + i];
        paf[gp * 4 + 2].u[i] = pk1[i];
        paf[gp * 4 + 3].u[i] = pk1[4 + i];
      }
    }
    psum += __shfl_xor(psum, 32);
    lsum += psum;

    __builtin_amdgcn_s_setprio(1);
#pragma unroll
    for (int db = 0; db < 4; ++db) {
      const char* vrow = vbuf + (db * 32 + ql) * 256;
#pragma unroll
      for (int kp = 0; kp < 8; ++kp) {
        int m = (kp * 2 + hl) ^ (ql & 15);
        bf16x8 vf = *(const bf16x8*)(vrow + m * 16);
        of[db] = MFMA32(vf, paf[kp].v, of[db]);
      }
    }
    __builtin_amdgcn_s_setprio(0);
    FENCE;
  }

  float linv = 1.f / (lsum + 1e-8f);
  size_t qrow_o = (size_t)(qb * 256 + w * 32 + ql) * 2048 + h * 128;
#pragma unroll
  for (int db = 0; db < 4; ++db)
#pragma unroll
    for (int u = 0; u < 4; ++u) {
      ushort4 pk;
      pk.x = f2bf(of[db][4 * u + 0] * linv);
      pk.y = f2bf(of[db][4 * u + 1] * linv);
      pk.z = f2bf(of[db][4 * u + 2] * linv);
      pk.w = f2bf(of[db][4 * u + 3] * linv);
      *(ushort4*)(og + qrow_o + db * 32 + 8 * u + hl * 4) = pk;
    }
}

// ---------------------------------------------------------------- launcher
extern "C" void kernel_launch(void* const* d_in, const int* in_sizes, int n_in,
                              void* d_out, int out_size, void* d_ws, size_t ws_size,
                              hipStream_t stream) {
  const float* x = (const float*)d_in[0];      // [4096][2048]
  const float* w_qkv = (const float*)d_in[1];  // [6144][2048]
  const float* w_out = (const float*)d_in[2];  // [2048][2048]

  char* ws = (char*)d_ws;
  u16* xb = (u16*)(ws + 0);            // 16 MB
  u16* wqkvb = (u16*)(ws + 16777216);  // 24 MB
  u16* woutb = (u16*)(ws + 41943040);  // 8 MB
  u16* qb = (u16*)(ws + 50331648);     // 16 MB  [NH][S][HD] (pre-scaled)
  u16* kb = (u16*)(ws + 67108864);     // 16 MB  [NH][S][HD]
  u16* vtb = (u16*)(ws + 83886080);    // 16 MB  [NH][HD][S]
  u16* aob = (u16*)(ws + 100663296);   // 16 MB  [S][H]

  cast_all<<<2048, 256, 0, stream>>>(x, w_qkv, w_out, xb, wqkvb, woutb);
  gemm8<0><<<768, 512, 0, stream>>>(xb, wqkvb, qb, kb, vtb, 4096, 6144, 2048, 32);
  attn_kernel<<<256, 512, 0, stream>>>(qb, kb, vtb, aob);
  gemm8<1><<<256, 512, 0, stream>>>(aob, woutb, d_out, nullptr, nullptr, 4096, 2048, 2048, 32);
}